// Round 2
// baseline (4010.412 us; speedup 1.0000x reference)
//
#include <hip/hip_runtime.h>
#include <math.h>

__global__ void zero_int_kernel(int* __restrict__ p, int n) {
    int i = blockIdx.x * blockDim.x + threadIdx.x;
    int stride = gridDim.x * blockDim.x;
    for (; i < n; i += stride) p[i] = 0;
}

__global__ void hist_kernel(const int* __restrict__ EI, int* __restrict__ cnt, int E) {
    int e = blockIdx.x * blockDim.x + threadIdx.x;
    if (e < E) atomicAdd(&cnt[EI[E + e]], 1);
}

// single-block exclusive scan over cnt[N] -> rowstart[N+1], cursor[N]
__global__ __launch_bounds__(1024)
void scan_kernel(const int* __restrict__ cnt, int* __restrict__ rowstart,
                 int* __restrict__ cursor, int N) {
    __shared__ int sbuf[1024];
    __shared__ int soff;
    int tid = threadIdx.x;
    if (tid == 0) soff = 0;
    __syncthreads();
    for (int base = 0; base < N; base += 1024) {
        int i = base + tid;
        int v = (i < N) ? cnt[i] : 0;
        sbuf[tid] = v;
        __syncthreads();
#pragma unroll
        for (int d = 1; d < 1024; d <<= 1) {
            int t = (tid >= d) ? sbuf[tid - d] : 0;
            __syncthreads();
            sbuf[tid] += t;
            __syncthreads();
        }
        int incl = sbuf[tid];
        int total = sbuf[1023];
        int my = soff + incl - v;
        if (i < N) { rowstart[i] = my; cursor[i] = my; }
        __syncthreads();
        if (tid == 0) soff += total;
        __syncthreads();
    }
    if (tid == 0) rowstart[N] = soff;
}

__global__ void fill_kernel(const int* __restrict__ EI, const float* __restrict__ EF,
                            int* __restrict__ cursor, int* __restrict__ srcs,
                            float* __restrict__ feats, int E) {
    int e = blockIdx.x * blockDim.x + threadIdx.x;
    if (e < E) {
        int dst = EI[E + e];
        int slot = atomicAdd(&cursor[dst], 1);
        srcs[slot] = EI[e];
        feats[slot] = EF[e];
    }
}

// first encoder layer: Y[n,j] = relu(b[j] + sum_{k<5} NF[n,k]*W[k,j])
__global__ __launch_bounds__(256)
void enc1_kernel(const float* __restrict__ NF, const float* __restrict__ W,
                 const float* __restrict__ b, float* __restrict__ Y, int N) {
    int lane = threadIdx.x & 63;
    float w0 = W[0 * 64 + lane], w1 = W[1 * 64 + lane], w2 = W[2 * 64 + lane];
    float w3 = W[3 * 64 + lane], w4 = W[4 * 64 + lane];
    float bv = b[lane];
    int wid = (blockIdx.x * blockDim.x + threadIdx.x) >> 6;
    int nw = (gridDim.x * blockDim.x) >> 6;
    for (int n = wid; n < N; n += nw) {
        float x = (lane < 5) ? NF[n * 5 + lane] : 0.f;
        float acc = bv;
        acc = fmaf(__shfl(x, 0), w0, acc);
        acc = fmaf(__shfl(x, 1), w1, acc);
        acc = fmaf(__shfl(x, 2), w2, acc);
        acc = fmaf(__shfl(x, 3), w3, acc);
        acc = fmaf(__shfl(x, 4), w4, acc);
        Y[n * 64 + lane] = fmaxf(acc, 0.f);
    }
}

// Y[n,j] = (relu?)(b[j] + sum_k X[n,k]*W[k,j]), K = 64, 2-row unroll
__global__ __launch_bounds__(256, 2)
void gemm64_kernel(const float* __restrict__ X, const float* __restrict__ W,
                   const float* __restrict__ b, float* __restrict__ Y,
                   int N, int doRelu) {
    int lane = threadIdx.x & 63;
    float wcol[64];
#pragma unroll
    for (int k = 0; k < 64; ++k) wcol[k] = W[k * 64 + lane];
    float bv = b[lane];
    int wid = (blockIdx.x * blockDim.x + threadIdx.x) >> 6;
    int nw = (gridDim.x * blockDim.x) >> 6;
    for (int n = wid * 2; n < N; n += nw * 2) {
        float x0 = X[(size_t)n * 64 + lane];
        bool has1 = (n + 1) < N;
        float x1 = has1 ? X[(size_t)(n + 1) * 64 + lane] : 0.f;
        float a0 = bv, a1 = bv;
#pragma unroll
        for (int k = 0; k < 64; ++k) {
            a0 = fmaf(__shfl(x0, k), wcol[k], a0);
            a1 = fmaf(__shfl(x1, k), wcol[k], a1);
        }
        if (doRelu) { a0 = fmaxf(a0, 0.f); a1 = fmaxf(a1, 0.f); }
        Y[(size_t)n * 64 + lane] = a0;
        if (has1) Y[(size_t)(n + 1) * 64 + lane] = a1;
    }
}

// gather-form fused message MLP + mean aggregation (no atomics):
// per dst node n: agg[n] = (1/max(deg,1)) * sum_{e in in(n)}
//     relu(W2^T relu(G[src_e] + relu(f_e*eW+eB)@W1b) + b2)
__global__ __launch_bounds__(256, 1)
void msg_gather_kernel(const float* __restrict__ G, const int* __restrict__ rowstart,
                       const int* __restrict__ srcs, const float* __restrict__ feats,
                       const float* __restrict__ eW, const float* __restrict__ eB,
                       const float* __restrict__ W1b, const float* __restrict__ W2,
                       const float* __restrict__ b2, float* __restrict__ Agg, int N) {
    int lane = threadIdx.x & 63;
    float w1c[64], w2c[64];
#pragma unroll
    for (int k = 0; k < 64; ++k) w1c[k] = W1b[k * 64 + lane];
#pragma unroll
    for (int k = 0; k < 64; ++k) w2c[k] = W2[k * 64 + lane];
    float ew = eW[lane], ebv = eB[lane], b2v = b2[lane];
    int wid = (blockIdx.x * blockDim.x + threadIdx.x) >> 6;
    int nw = (gridDim.x * blockDim.x) >> 6;
    for (int n = wid; n < N; n += nw) {
        int beg = rowstart[n], end = rowstart[n + 1];
        float acc = 0.f;
        int e = beg;
        for (; e + 1 < end; e += 2) {
            int s0 = srcs[e], s1 = srcs[e + 1];
            float f0 = feats[e], f1 = feats[e + 1];
            float g0 = G[(size_t)s0 * 64 + lane];
            float g1 = G[(size_t)s1 * 64 + lane];
            float eh0 = fmaxf(fmaf(f0, ew, ebv), 0.f);
            float eh1 = fmaxf(fmaf(f1, ew, ebv), 0.f);
            float c0 = 0.f, c1 = 0.f;
#pragma unroll
            for (int k = 0; k < 64; ++k) {
                c0 = fmaf(__shfl(eh0, k), w1c[k], c0);
                c1 = fmaf(__shfl(eh1, k), w1c[k], c1);
            }
            float h0 = fmaxf(g0 + c0, 0.f);
            float h1 = fmaxf(g1 + c1, 0.f);
            float m0 = b2v, m1 = b2v;
#pragma unroll
            for (int k = 0; k < 64; ++k) {
                m0 = fmaf(__shfl(h0, k), w2c[k], m0);
                m1 = fmaf(__shfl(h1, k), w2c[k], m1);
            }
            acc += fmaxf(m0, 0.f) + fmaxf(m1, 0.f);
        }
        if (e < end) {
            int s0 = srcs[e];
            float f0 = feats[e];
            float g0 = G[(size_t)s0 * 64 + lane];
            float eh0 = fmaxf(fmaf(f0, ew, ebv), 0.f);
            float c0 = 0.f;
#pragma unroll
            for (int k = 0; k < 64; ++k) c0 = fmaf(__shfl(eh0, k), w1c[k], c0);
            float h0 = fmaxf(g0 + c0, 0.f);
            float m0 = b2v;
#pragma unroll
            for (int k = 0; k < 64; ++k) m0 = fmaf(__shfl(h0, k), w2c[k], m0);
            acc += fmaxf(m0, 0.f);
        }
        float inv = 1.f / fmaxf((float)(end - beg), 1.f);
        Agg[(size_t)n * 64 + lane] = acc * inv;
    }
}

// update layer 1: Y[n,j] = relu(b1[j] + sum_k Hc[n,k]*U1[k,j] + sum_k Agg[n,k]*U1[64+k,j])
__global__ __launch_bounds__(256, 2)
void upd1_kernel(const float* __restrict__ Hc, const float* __restrict__ Agg,
                 const float* __restrict__ U1, const float* __restrict__ b1,
                 float* __restrict__ Y, int N) {
    int lane = threadIdx.x & 63;
    float ua[64], ub[64];
#pragma unroll
    for (int k = 0; k < 64; ++k) ua[k] = U1[k * 64 + lane];
#pragma unroll
    for (int k = 0; k < 64; ++k) ub[k] = U1[(64 + k) * 64 + lane];
    float bv = b1[lane];
    int wid = (blockIdx.x * blockDim.x + threadIdx.x) >> 6;
    int nw = (gridDim.x * blockDim.x) >> 6;
    for (int n = wid; n < N; n += nw) {
        float x = Hc[(size_t)n * 64 + lane];
        float a = Agg[(size_t)n * 64 + lane];
        float acc = bv, acc2 = 0.f;
#pragma unroll
        for (int k = 0; k < 64; ++k) {
            acc = fmaf(__shfl(x, k), ua[k], acc);
            acc2 = fmaf(__shfl(a, k), ub[k], acc2);
        }
        Y[(size_t)n * 64 + lane] = fmaxf(acc + acc2, 0.f);
    }
}

// head: t = relu(Hc@W1 + b1); pred[c] = sum_j t[j]*W2[j,c] + b2[c]; out = 2pi*sigmoid(pred)
__global__ __launch_bounds__(256, 2)
void head_kernel(const float* __restrict__ Hc, const float* __restrict__ W1,
                 const float* __restrict__ b1, const float* __restrict__ W2,
                 const float* __restrict__ b2, float* __restrict__ out, int N) {
    int lane = threadIdx.x & 63;
    float wcol[64];
#pragma unroll
    for (int k = 0; k < 64; ++k) wcol[k] = W1[k * 64 + lane];
    float bv = b1[lane];
    float w2c0 = W2[lane * 3 + 0], w2c1 = W2[lane * 3 + 1], w2c2 = W2[lane * 3 + 2];
    float b20 = b2[0], b21 = b2[1], b22 = b2[2];
    int wid = (blockIdx.x * blockDim.x + threadIdx.x) >> 6;
    int nw = (gridDim.x * blockDim.x) >> 6;
    const float TWO_PI = 6.283185307179586f;
    for (int n = wid; n < N; n += nw) {
        float x = Hc[(size_t)n * 64 + lane];
        float t = bv;
#pragma unroll
        for (int k = 0; k < 64; ++k) t = fmaf(__shfl(x, k), wcol[k], t);
        t = fmaxf(t, 0.f);
        float p0 = t * w2c0, p1 = t * w2c1, p2 = t * w2c2;
#pragma unroll
        for (int off = 32; off > 0; off >>= 1) {
            p0 += __shfl_xor(p0, off);
            p1 += __shfl_xor(p1, off);
            p2 += __shfl_xor(p2, off);
        }
        if (lane == 0) {
            float v0 = p0 + b20, v1 = p1 + b21, v2 = p2 + b22;
            out[n * 3 + 0] = TWO_PI / (1.f + expf(-v0));
            out[n * 3 + 1] = TWO_PI / (1.f + expf(-v1));
            out[n * 3 + 2] = TWO_PI / (1.f + expf(-v2));
        }
    }
}

extern "C" void kernel_launch(void* const* d_in, const int* in_sizes, int n_in,
                              void* d_out, int out_size, void* d_ws, size_t ws_size,
                              hipStream_t stream) {
    const float* nf    = (const float*)d_in[0];
    const int*   ei    = (const int*)d_in[1];
    const float* ef    = (const float*)d_in[2];
    const float* encW1 = (const float*)d_in[3];
    const float* encb1 = (const float*)d_in[4];
    const float* encW2 = (const float*)d_in[5];
    const float* encb2 = (const float*)d_in[6];
    const float* eeW   = (const float*)d_in[7];
    const float* eeb   = (const float*)d_in[8];
    const float* mW1   = (const float*)d_in[9];
    const float* mb1   = (const float*)d_in[10];
    const float* mW2   = (const float*)d_in[11];
    const float* mb2   = (const float*)d_in[12];
    const float* uW1   = (const float*)d_in[13];
    const float* ub1   = (const float*)d_in[14];
    const float* uW2   = (const float*)d_in[15];
    const float* ub2   = (const float*)d_in[16];
    const float* oW1   = (const float*)d_in[17];
    const float* ob1   = (const float*)d_in[18];
    const float* oW2   = (const float*)d_in[19];
    const float* ob2   = (const float*)d_in[20];
    float* out = (float*)d_out;

    int N = in_sizes[0] / 5;   // 50000
    int E = in_sizes[2];       // 800000

    float* ws  = (float*)d_ws;
    float* h   = ws;
    float* hn  = ws + (size_t)N * 64;
    float* g   = ws + (size_t)2 * N * 64;
    float* agg = ws + (size_t)3 * N * 64;
    int* ip       = (int*)(ws + (size_t)4 * N * 64);
    int* rowstart = ip;                 // N+1
    int* cursor   = rowstart + (N + 1); // N
    int* dcnt     = cursor + N;         // N
    int* srcs     = dcnt + N;           // E
    float* feats  = (float*)(srcs + E); // E

    // node encoder
    enc1_kernel<<<512, 256, 0, stream>>>(nf, encW1, encb1, g, N);
    gemm64_kernel<<<1024, 256, 0, stream>>>(g, encW2, encb2, h, N, 1);

    // CSR build (dst-sorted edge list), reused by all 3 layers
    zero_int_kernel<<<256, 256, 0, stream>>>(dcnt, N);
    hist_kernel<<<(E + 255) / 256, 256, 0, stream>>>(ei, dcnt, E);
    scan_kernel<<<1, 1024, 0, stream>>>(dcnt, rowstart, cursor, N);
    fill_kernel<<<(E + 255) / 256, 256, 0, stream>>>(ei, ef, cursor, srcs, feats, E);

    for (int l = 0; l < 3; ++l) {
        const float* W1a = mW1 + (size_t)l * 128 * 64;
        const float* W1b = W1a + 64 * 64;
        const float* b1  = mb1 + l * 64;
        const float* W2  = mW2 + (size_t)l * 64 * 64;
        const float* b2  = mb2 + l * 64;
        // g = h @ W1a + b1   (src-side half of the concat matmul, per node)
        gemm64_kernel<<<1024, 256, 0, stream>>>(h, W1a, b1, g, N, 0);
        msg_gather_kernel<<<2048, 256, 0, stream>>>(g, rowstart, srcs, feats,
                                                    eeW, eeb, W1b, W2, b2, agg, N);
        const float* U1 = uW1 + (size_t)l * 128 * 64;
        const float* v1 = ub1 + l * 64;
        const float* U2 = uW2 + (size_t)l * 64 * 64;
        const float* v2 = ub2 + l * 64;
        upd1_kernel<<<1024, 256, 0, stream>>>(h, agg, U1, v1, g, N);
        gemm64_kernel<<<1024, 256, 0, stream>>>(g, U2, v2, hn, N, 1);
        float* tmp = h; h = hn; hn = tmp;
    }

    head_kernel<<<1024, 256, 0, stream>>>(h, oW1, ob1, oW2, ob2, out, N);
}

// Round 3
// 1272.894 us; speedup vs baseline: 3.1506x; 3.1506x over previous
//
#include <hip/hip_runtime.h>
#include <math.h>

__device__ __forceinline__ float readlane_f(float v, int l) {
    return __uint_as_float(__builtin_amdgcn_readlane(__float_as_uint(v), l));
}

__global__ void zero_int_kernel(int* __restrict__ p, int n) {
    int i = blockIdx.x * blockDim.x + threadIdx.x;
    int stride = gridDim.x * blockDim.x;
    for (; i < n; i += stride) p[i] = 0;
}

__global__ void hist_kernel(const int* __restrict__ EI, int* __restrict__ cnt, int E) {
    int e = blockIdx.x * blockDim.x + threadIdx.x;
    if (e < E) atomicAdd(&cnt[EI[E + e]], 1);
}

// single-block exclusive scan over cnt[N] -> rowstart[N+1], cursor[N]
__global__ __launch_bounds__(1024)
void scan_kernel(const int* __restrict__ cnt, int* __restrict__ rowstart,
                 int* __restrict__ cursor, int N) {
    __shared__ int sbuf[1024];
    __shared__ int soff;
    int tid = threadIdx.x;
    if (tid == 0) soff = 0;
    __syncthreads();
    for (int base = 0; base < N; base += 1024) {
        int i = base + tid;
        int v = (i < N) ? cnt[i] : 0;
        sbuf[tid] = v;
        __syncthreads();
#pragma unroll
        for (int d = 1; d < 1024; d <<= 1) {
            int t = (tid >= d) ? sbuf[tid - d] : 0;
            __syncthreads();
            sbuf[tid] += t;
            __syncthreads();
        }
        int incl = sbuf[tid];
        int total = sbuf[1023];
        int my = soff + incl - v;
        if (i < N) { rowstart[i] = my; cursor[i] = my; }
        __syncthreads();
        if (tid == 0) soff += total;
        __syncthreads();
    }
    if (tid == 0) rowstart[N] = soff;
}

__global__ void fill_kernel(const int* __restrict__ EI, const float* __restrict__ EF,
                            int* __restrict__ cursor, int* __restrict__ srcs,
                            float* __restrict__ feats, int E) {
    int e = blockIdx.x * blockDim.x + threadIdx.x;
    if (e < E) {
        int dst = EI[E + e];
        int slot = atomicAdd(&cursor[dst], 1);
        srcs[slot] = EI[e];
        feats[slot] = EF[e];
    }
}

// sorted breakpoints of f -> relu(f*eW+eB): t_k = -eB_k/eW_k (eW_k != 0)
__global__ __launch_bounds__(64)
void bp_kernel(const float* __restrict__ eW, const float* __restrict__ eB,
               float* __restrict__ bp) {
    int lane = threadIdx.x;
    float w = eW[lane], b = eB[lane];
    float t = (w != 0.f) ? (-b / w) : 1e30f;
    __shared__ float sbp[64];
    int rank = 0;
    for (int j = 0; j < 64; ++j) {
        float tj = readlane_f(t, j);
        rank += (tj < t) || (tj == t && j < lane);
    }
    sbp[rank] = t;
    __syncthreads();
    bp[lane] = sbp[lane];
}

// per (layer, segment): A[j] = sum_{k active} eB_k*W1b[k][j], B[j] = sum eW_k*W1b[k][j]
__global__ __launch_bounds__(64)
void tab_kernel(const float* __restrict__ eW, const float* __restrict__ eB,
                const float* __restrict__ mW1, const float* __restrict__ bp,
                float* __restrict__ Atab, float* __restrict__ Btab) {
    int s = blockIdx.x % 65;
    int l = blockIdx.x / 65;
    int j = threadIdx.x;
    float lo = (s == 0) ? 0.f : bp[s - 1];
    float hi = (s == 64) ? 0.f : bp[s];
    float rep;
    if (s == 0) rep = hi - fmaxf(1.f, fabsf(hi));
    else if (s == 64) rep = lo + fmaxf(1.f, fabsf(lo));
    else rep = 0.5f * (lo + hi);
    const float* W1b = mW1 + (size_t)l * 128 * 64 + 64 * 64;
    float A = 0.f, B = 0.f;
    for (int k = 0; k < 64; ++k) {
        float w = eW[k], b = eB[k];
        if (fmaf(rep, w, b) > 0.f) {
            float wv = W1b[k * 64 + j];
            A = fmaf(b, wv, A);
            B = fmaf(w, wv, B);
        }
    }
    Atab[((size_t)l * 65 + s) * 64 + j] = A;
    Btab[((size_t)l * 65 + s) * 64 + j] = B;
}

// first encoder layer: Y[n,j] = relu(b[j] + sum_{k<5} NF[n,k]*W[k,j])
__global__ __launch_bounds__(256)
void enc1_kernel(const float* __restrict__ NF, const float* __restrict__ W,
                 const float* __restrict__ b, float* __restrict__ Y, int N) {
    int lane = threadIdx.x & 63;
    float w0 = W[0 * 64 + lane], w1 = W[1 * 64 + lane], w2 = W[2 * 64 + lane];
    float w3 = W[3 * 64 + lane], w4 = W[4 * 64 + lane];
    float bv = b[lane];
    int wid = (blockIdx.x * blockDim.x + threadIdx.x) >> 6;
    int nw = (gridDim.x * blockDim.x) >> 6;
    for (int n = wid; n < N; n += nw) {
        float x = (lane < 5) ? NF[n * 5 + lane] : 0.f;
        float acc = bv;
        acc = fmaf(readlane_f(x, 0), w0, acc);
        acc = fmaf(readlane_f(x, 1), w1, acc);
        acc = fmaf(readlane_f(x, 2), w2, acc);
        acc = fmaf(readlane_f(x, 3), w3, acc);
        acc = fmaf(readlane_f(x, 4), w4, acc);
        Y[n * 64 + lane] = fmaxf(acc, 0.f);
    }
}

// Y[n,j] = act( Z?[n,:] + X[n,:]@W + b? ), K=64, 2-row unroll, readlane broadcast
template <int HAS_Z, int RELU, int HAS_B>
__global__ __launch_bounds__(256, 4)
void gemm64_kernel(const float* __restrict__ X, const float* __restrict__ W,
                   const float* __restrict__ b, const float* __restrict__ Z,
                   float* __restrict__ Y, int N) {
    int lane = threadIdx.x & 63;
    float wcol[64];
#pragma unroll
    for (int k = 0; k < 64; ++k) wcol[k] = W[k * 64 + lane];
    float bv = HAS_B ? b[lane] : 0.f;
    int wid = (blockIdx.x * blockDim.x + threadIdx.x) >> 6;
    int nw = (gridDim.x * blockDim.x) >> 6;
    for (int n = wid * 2; n < N; n += nw * 2) {
        bool has1 = (n + 1) < N;
        float x0 = X[(size_t)n * 64 + lane];
        float x1 = has1 ? X[(size_t)(n + 1) * 64 + lane] : 0.f;
        float a0 = bv, a1 = bv;
        if (HAS_Z) {
            a0 += Z[(size_t)n * 64 + lane];
            if (has1) a1 += Z[(size_t)(n + 1) * 64 + lane];
        }
#pragma unroll
        for (int k = 0; k < 64; ++k) {
            a0 = fmaf(readlane_f(x0, k), wcol[k], a0);
            a1 = fmaf(readlane_f(x1, k), wcol[k], a1);
        }
        if (RELU) { a0 = fmaxf(a0, 0.f); a1 = fmaxf(a1, 0.f); }
        Y[(size_t)n * 64 + lane] = a0;
        if (has1) Y[(size_t)(n + 1) * 64 + lane] = a1;
    }
}

// gather-form fused message MLP + mean agg; edge-encoder matmul replaced by
// piecewise-linear table: ce = A[seg] + f*B[seg], seg = popc(ballot(f > bp))
__global__ __launch_bounds__(256, 4)
void msg_gather2_kernel(const float* __restrict__ G, const int* __restrict__ rowstart,
                        const int* __restrict__ srcs, const float* __restrict__ feats,
                        const float* __restrict__ bp, const float* __restrict__ Atab,
                        const float* __restrict__ Btab, const float* __restrict__ W2,
                        const float* __restrict__ b2, float* __restrict__ Agg, int N) {
    __shared__ float sA[65 * 64], sB[65 * 64];
    int tid = threadIdx.x;
    for (int i = tid; i < 65 * 64; i += 256) { sA[i] = Atab[i]; sB[i] = Btab[i]; }
    __syncthreads();
    int lane = tid & 63;
    float bpl = bp[lane];
    float w2c[64];
#pragma unroll
    for (int k = 0; k < 64; ++k) w2c[k] = W2[k * 64 + lane];
    float b2v = b2[lane];
    int wid = (blockIdx.x * blockDim.x + tid) >> 6;
    int nw = (gridDim.x * blockDim.x) >> 6;
    for (int n = wid; n < N; n += nw) {
        int beg = rowstart[n], end = rowstart[n + 1];
        float acc = 0.f;
        int e = beg;
        for (; e + 1 < end; e += 2) {
            float f0 = feats[e], f1 = feats[e + 1];
            int s0 = srcs[e], s1 = srcs[e + 1];
            int seg0 = __popcll(__ballot(f0 > bpl));
            int seg1 = __popcll(__ballot(f1 > bpl));
            float ce0 = fmaf(f0, sB[seg0 * 64 + lane], sA[seg0 * 64 + lane]);
            float ce1 = fmaf(f1, sB[seg1 * 64 + lane], sA[seg1 * 64 + lane]);
            float g0 = G[(size_t)s0 * 64 + lane];
            float g1 = G[(size_t)s1 * 64 + lane];
            float h0 = fmaxf(g0 + ce0, 0.f);
            float h1 = fmaxf(g1 + ce1, 0.f);
            float m0 = b2v, m1 = b2v;
#pragma unroll
            for (int k = 0; k < 64; ++k) {
                m0 = fmaf(readlane_f(h0, k), w2c[k], m0);
                m1 = fmaf(readlane_f(h1, k), w2c[k], m1);
            }
            acc += fmaxf(m0, 0.f) + fmaxf(m1, 0.f);
        }
        if (e < end) {
            float f0 = feats[e];
            int s0 = srcs[e];
            int seg0 = __popcll(__ballot(f0 > bpl));
            float ce0 = fmaf(f0, sB[seg0 * 64 + lane], sA[seg0 * 64 + lane]);
            float g0 = G[(size_t)s0 * 64 + lane];
            float h0 = fmaxf(g0 + ce0, 0.f);
            float m0 = b2v;
#pragma unroll
            for (int k = 0; k < 64; ++k) m0 = fmaf(readlane_f(h0, k), w2c[k], m0);
            acc += fmaxf(m0, 0.f);
        }
        float inv = 1.f / fmaxf((float)(end - beg), 1.f);
        Agg[(size_t)n * 64 + lane] = acc * inv;
    }
}

// head: t = relu(Hc@W1 + b1); pred[c] = sum_j t[j]*W2[j,c] + b2[c]; out = 2pi*sigmoid(pred)
__global__ __launch_bounds__(256, 4)
void head_kernel(const float* __restrict__ Hc, const float* __restrict__ W1,
                 const float* __restrict__ b1, const float* __restrict__ W2,
                 const float* __restrict__ b2, float* __restrict__ out, int N) {
    int lane = threadIdx.x & 63;
    float wcol[64];
#pragma unroll
    for (int k = 0; k < 64; ++k) wcol[k] = W1[k * 64 + lane];
    float bv = b1[lane];
    float w2c0 = W2[lane * 3 + 0], w2c1 = W2[lane * 3 + 1], w2c2 = W2[lane * 3 + 2];
    float b20 = b2[0], b21 = b2[1], b22 = b2[2];
    int wid = (blockIdx.x * blockDim.x + threadIdx.x) >> 6;
    int nw = (gridDim.x * blockDim.x) >> 6;
    const float TWO_PI = 6.283185307179586f;
    for (int n = wid; n < N; n += nw) {
        float x = Hc[(size_t)n * 64 + lane];
        float t = bv;
#pragma unroll
        for (int k = 0; k < 64; ++k) t = fmaf(readlane_f(x, k), wcol[k], t);
        t = fmaxf(t, 0.f);
        float p0 = t * w2c0, p1 = t * w2c1, p2 = t * w2c2;
#pragma unroll
        for (int off = 32; off > 0; off >>= 1) {
            p0 += __shfl_xor(p0, off);
            p1 += __shfl_xor(p1, off);
            p2 += __shfl_xor(p2, off);
        }
        if (lane == 0) {
            float v0 = p0 + b20, v1 = p1 + b21, v2 = p2 + b22;
            out[n * 3 + 0] = TWO_PI / (1.f + expf(-v0));
            out[n * 3 + 1] = TWO_PI / (1.f + expf(-v1));
            out[n * 3 + 2] = TWO_PI / (1.f + expf(-v2));
        }
    }
}

extern "C" void kernel_launch(void* const* d_in, const int* in_sizes, int n_in,
                              void* d_out, int out_size, void* d_ws, size_t ws_size,
                              hipStream_t stream) {
    const float* nf    = (const float*)d_in[0];
    const int*   ei    = (const int*)d_in[1];
    const float* ef    = (const float*)d_in[2];
    const float* encW1 = (const float*)d_in[3];
    const float* encb1 = (const float*)d_in[4];
    const float* encW2 = (const float*)d_in[5];
    const float* encb2 = (const float*)d_in[6];
    const float* eeW   = (const float*)d_in[7];
    const float* eeb   = (const float*)d_in[8];
    const float* mW1   = (const float*)d_in[9];
    const float* mb1   = (const float*)d_in[10];
    const float* mW2   = (const float*)d_in[11];
    const float* mb2   = (const float*)d_in[12];
    const float* uW1   = (const float*)d_in[13];
    const float* ub1   = (const float*)d_in[14];
    const float* uW2   = (const float*)d_in[15];
    const float* ub2   = (const float*)d_in[16];
    const float* oW1   = (const float*)d_in[17];
    const float* ob1   = (const float*)d_in[18];
    const float* oW2   = (const float*)d_in[19];
    const float* ob2   = (const float*)d_in[20];
    float* out = (float*)d_out;

    int N = in_sizes[0] / 5;   // 50000
    int E = in_sizes[2];       // 800000
    size_t N64 = (size_t)N * 64;

    float* ws  = (float*)d_ws;
    float* h   = ws;
    float* hn  = ws + N64;
    float* g   = ws + 2 * N64;   // also reused as t1 in the update phase
    float* agg = ws + 3 * N64;
    int* rowstart = (int*)(ws + 4 * N64);  // N+1
    int* cursor   = rowstart + (N + 1);    // N
    int* dcnt     = cursor + N;            // N
    int* srcs     = dcnt + N;              // E
    float* feats  = (float*)(srcs + E);    // E
    float* bp     = feats + E;             // 64
    float* Atab   = bp + 64;               // 3*65*64
    float* Btab   = Atab + 3 * 65 * 64;    // 3*65*64

    // piecewise-linear tables for the edge-encoder->W1b path (fixed inputs)
    bp_kernel<<<1, 64, 0, stream>>>(eeW, eeb, bp);
    tab_kernel<<<195, 64, 0, stream>>>(eeW, eeb, mW1, bp, Atab, Btab);

    // node encoder
    enc1_kernel<<<512, 256, 0, stream>>>(nf, encW1, encb1, g, N);
    gemm64_kernel<0, 1, 1><<<1024, 256, 0, stream>>>(g, encW2, encb2, nullptr, h, N);

    // CSR build (dst-sorted edge list), reused by all 3 layers
    zero_int_kernel<<<256, 256, 0, stream>>>(dcnt, N);
    hist_kernel<<<(E + 255) / 256, 256, 0, stream>>>(ei, dcnt, E);
    scan_kernel<<<1, 1024, 0, stream>>>(dcnt, rowstart, cursor, N);
    fill_kernel<<<(E + 255) / 256, 256, 0, stream>>>(ei, ef, cursor, srcs, feats, E);

    for (int l = 0; l < 3; ++l) {
        const float* W1a = mW1 + (size_t)l * 128 * 64;
        const float* b1  = mb1 + l * 64;
        const float* W2  = mW2 + (size_t)l * 64 * 64;
        const float* b2  = mb2 + l * 64;
        // g = h @ W1a + b1 (src-side half of message concat-matmul, per node)
        gemm64_kernel<0, 0, 1><<<1024, 256, 0, stream>>>(h, W1a, b1, nullptr, g, N);
        msg_gather2_kernel<<<1024, 256, 0, stream>>>(g, rowstart, srcs, feats, bp,
                                                     Atab + (size_t)l * 65 * 64,
                                                     Btab + (size_t)l * 65 * 64,
                                                     W2, b2, agg, N);
        const float* U1a = uW1 + (size_t)l * 128 * 64;
        const float* U1b = U1a + 64 * 64;
        const float* v1  = ub1 + l * 64;
        const float* U2  = uW2 + (size_t)l * 64 * 64;
        const float* v2  = ub2 + l * 64;
        // t1 (=g) = h@U1a + b1 ; agg = relu(t1 + agg@U1b) ; hn = relu(agg@U2 + b2)
        gemm64_kernel<0, 0, 1><<<1024, 256, 0, stream>>>(h, U1a, v1, nullptr, g, N);
        gemm64_kernel<1, 1, 0><<<1024, 256, 0, stream>>>(agg, U1b, nullptr, g, agg, N);
        gemm64_kernel<0, 1, 1><<<1024, 256, 0, stream>>>(agg, U2, v2, nullptr, hn, N);
        float* tmp = h; h = hn; hn = tmp;
    }

    head_kernel<<<1024, 256, 0, stream>>>(h, oW1, ob1, oW2, ob2, out, N);
}

// Round 4
// 1192.563 us; speedup vs baseline: 3.3629x; 1.0674x over previous
//
#include <hip/hip_runtime.h>
#include <math.h>

__device__ __forceinline__ float readlane_f(float v, int l) {
    return __uint_as_float(__builtin_amdgcn_readlane(__float_as_uint(v), l));
}

__global__ void zero_int_kernel(int* __restrict__ p, int n) {
    int i = blockIdx.x * blockDim.x + threadIdx.x;
    int stride = gridDim.x * blockDim.x;
    for (; i < n; i += stride) p[i] = 0;
}

__global__ void hist_kernel(const int* __restrict__ EI, int* __restrict__ cnt, int E) {
    int e = blockIdx.x * blockDim.x + threadIdx.x;
    if (e < E) atomicAdd(&cnt[EI[E + e]], 1);
}

// single-block exclusive scan over cnt[N] -> rowstart[N+1], cursor[N]
__global__ __launch_bounds__(1024)
void scan_kernel(const int* __restrict__ cnt, int* __restrict__ rowstart,
                 int* __restrict__ cursor, int N) {
    __shared__ int sbuf[1024];
    __shared__ int soff;
    int tid = threadIdx.x;
    if (tid == 0) soff = 0;
    __syncthreads();
    for (int base = 0; base < N; base += 1024) {
        int i = base + tid;
        int v = (i < N) ? cnt[i] : 0;
        sbuf[tid] = v;
        __syncthreads();
#pragma unroll
        for (int d = 1; d < 1024; d <<= 1) {
            int t = (tid >= d) ? sbuf[tid - d] : 0;
            __syncthreads();
            sbuf[tid] += t;
            __syncthreads();
        }
        int incl = sbuf[tid];
        int total = sbuf[1023];
        int my = soff + incl - v;
        if (i < N) { rowstart[i] = my; cursor[i] = my; }
        __syncthreads();
        if (tid == 0) soff += total;
        __syncthreads();
    }
    if (tid == 0) rowstart[N] = soff;
}

__global__ void fill_kernel(const int* __restrict__ EI, const float* __restrict__ EF,
                            int* __restrict__ cursor, int* __restrict__ srcs,
                            float* __restrict__ feats, int E) {
    int e = blockIdx.x * blockDim.x + threadIdx.x;
    if (e < E) {
        int dst = EI[E + e];
        int slot = atomicAdd(&cursor[dst], 1);
        srcs[slot] = EI[e];
        feats[slot] = EF[e];
    }
}

// sorted breakpoints of f -> relu(f*eW+eB): t_k = -eB_k/eW_k (eW_k != 0)
__global__ __launch_bounds__(64)
void bp_kernel(const float* __restrict__ eW, const float* __restrict__ eB,
               float* __restrict__ bp) {
    int lane = threadIdx.x;
    float w = eW[lane], b = eB[lane];
    float t = (w != 0.f) ? (-b / w) : 1e30f;
    __shared__ float sbp[64];
    int rank = 0;
    for (int j = 0; j < 64; ++j) {
        float tj = readlane_f(t, j);
        rank += (tj < t) || (tj == t && j < lane);
    }
    sbp[rank] = t;
    __syncthreads();
    bp[lane] = sbp[lane];
}

// per (layer, segment): A[j] = sum_{k active} eB_k*W1b[k][j], B[j] = sum eW_k*W1b[k][j]
__global__ __launch_bounds__(64)
void tab_kernel(const float* __restrict__ eW, const float* __restrict__ eB,
                const float* __restrict__ mW1, const float* __restrict__ bp,
                float* __restrict__ Atab, float* __restrict__ Btab) {
    int s = blockIdx.x % 65;
    int l = blockIdx.x / 65;
    int j = threadIdx.x;
    float lo = (s == 0) ? 0.f : bp[s - 1];
    float hi = (s == 64) ? 0.f : bp[s];
    float rep;
    if (s == 0) rep = hi - fmaxf(1.f, fabsf(hi));
    else if (s == 64) rep = lo + fmaxf(1.f, fabsf(lo));
    else rep = 0.5f * (lo + hi);
    const float* W1b = mW1 + (size_t)l * 128 * 64 + 64 * 64;
    float A = 0.f, B = 0.f;
    for (int k = 0; k < 64; ++k) {
        float w = eW[k], b = eB[k];
        if (fmaf(rep, w, b) > 0.f) {
            float wv = W1b[k * 64 + j];
            A = fmaf(b, wv, A);
            B = fmaf(w, wv, B);
        }
    }
    Atab[((size_t)l * 65 + s) * 64 + j] = A;
    Btab[((size_t)l * 65 + s) * 64 + j] = B;
}

// first encoder layer: Y[n,j] = relu(b[j] + sum_{k<5} NF[n,k]*W[k,j])
__global__ __launch_bounds__(256)
void enc1_kernel(const float* __restrict__ NF, const float* __restrict__ W,
                 const float* __restrict__ b, float* __restrict__ Y, int N) {
    int lane = threadIdx.x & 63;
    float w0 = W[0 * 64 + lane], w1 = W[1 * 64 + lane], w2 = W[2 * 64 + lane];
    float w3 = W[3 * 64 + lane], w4 = W[4 * 64 + lane];
    float bv = b[lane];
    int wid = (blockIdx.x * blockDim.x + threadIdx.x) >> 6;
    int nw = (gridDim.x * blockDim.x) >> 6;
    for (int n = wid; n < N; n += nw) {
        float x = (lane < 5) ? NF[n * 5 + lane] : 0.f;
        float acc = bv;
        acc = fmaf(readlane_f(x, 0), w0, acc);
        acc = fmaf(readlane_f(x, 1), w1, acc);
        acc = fmaf(readlane_f(x, 2), w2, acc);
        acc = fmaf(readlane_f(x, 3), w3, acc);
        acc = fmaf(readlane_f(x, 4), w4, acc);
        Y[n * 64 + lane] = fmaxf(acc, 0.f);
    }
}

// Y[n,j] = act( Z?[n,:] + X[n,:]@W + b? ), K=64, 4-row unroll, readlane broadcast
template <int HAS_Z, int RELU, int HAS_B>
__global__ __launch_bounds__(256, 2)
void gemm64_kernel(const float* __restrict__ X, const float* __restrict__ W,
                   const float* __restrict__ b, const float* __restrict__ Z,
                   float* __restrict__ Y, int N) {
    int lane = threadIdx.x & 63;
    float wcol[64];
#pragma unroll
    for (int k = 0; k < 64; ++k) wcol[k] = W[k * 64 + lane];
    float bv = HAS_B ? b[lane] : 0.f;
    int wid = (blockIdx.x * blockDim.x + threadIdx.x) >> 6;
    int nw = (gridDim.x * blockDim.x) >> 6;
    for (int n0 = wid * 4; n0 < N; n0 += nw * 4) {
        int nrem = N - n0;
        if (nrem >= 4) {
            float x0 = X[(size_t)n0 * 64 + lane];
            float x1 = X[(size_t)(n0 + 1) * 64 + lane];
            float x2 = X[(size_t)(n0 + 2) * 64 + lane];
            float x3 = X[(size_t)(n0 + 3) * 64 + lane];
            float a0 = bv, a1 = bv, a2 = bv, a3 = bv;
            if (HAS_Z) {
                a0 += Z[(size_t)n0 * 64 + lane];
                a1 += Z[(size_t)(n0 + 1) * 64 + lane];
                a2 += Z[(size_t)(n0 + 2) * 64 + lane];
                a3 += Z[(size_t)(n0 + 3) * 64 + lane];
            }
#pragma unroll
            for (int k = 0; k < 64; ++k) {
                a0 = fmaf(readlane_f(x0, k), wcol[k], a0);
                a1 = fmaf(readlane_f(x1, k), wcol[k], a1);
                a2 = fmaf(readlane_f(x2, k), wcol[k], a2);
                a3 = fmaf(readlane_f(x3, k), wcol[k], a3);
            }
            if (RELU) {
                a0 = fmaxf(a0, 0.f); a1 = fmaxf(a1, 0.f);
                a2 = fmaxf(a2, 0.f); a3 = fmaxf(a3, 0.f);
            }
            Y[(size_t)n0 * 64 + lane] = a0;
            Y[(size_t)(n0 + 1) * 64 + lane] = a1;
            Y[(size_t)(n0 + 2) * 64 + lane] = a2;
            Y[(size_t)(n0 + 3) * 64 + lane] = a3;
        } else {
            for (int n = n0; n < N; ++n) {
                float x0 = X[(size_t)n * 64 + lane];
                float a0 = bv;
                if (HAS_Z) a0 += Z[(size_t)n * 64 + lane];
#pragma unroll
                for (int k = 0; k < 64; ++k) a0 = fmaf(readlane_f(x0, k), wcol[k], a0);
                if (RELU) a0 = fmaxf(a0, 0.f);
                Y[(size_t)n * 64 + lane] = a0;
            }
        }
    }
}

// gather-form fused message MLP + mean agg; edge-encoder matmul replaced by
// piecewise-linear table: ce = A[seg] + f*B[seg], seg = popc(ballot(f > bp))
__global__ __launch_bounds__(256, 2)
void msg_gather2_kernel(const float* __restrict__ G, const int* __restrict__ rowstart,
                        const int* __restrict__ srcs, const float* __restrict__ feats,
                        const float* __restrict__ bp, const float* __restrict__ Atab,
                        const float* __restrict__ Btab, const float* __restrict__ W2,
                        const float* __restrict__ b2, float* __restrict__ Agg, int N) {
    __shared__ float sA[65 * 64], sB[65 * 64];
    int tid = threadIdx.x;
    for (int i = tid; i < 65 * 64; i += 256) { sA[i] = Atab[i]; sB[i] = Btab[i]; }
    __syncthreads();
    int lane = tid & 63;
    float bpl = bp[lane];
    float w2c[64];
#pragma unroll
    for (int k = 0; k < 64; ++k) w2c[k] = W2[k * 64 + lane];
    float b2v = b2[lane];
    int wid = (blockIdx.x * blockDim.x + tid) >> 6;
    int nw = (gridDim.x * blockDim.x) >> 6;
    for (int n = wid; n < N; n += nw) {
        int beg = rowstart[n], end = rowstart[n + 1];
        float acc = 0.f;
        int e = beg;
        for (; e + 3 < end; e += 4) {
            float f0 = feats[e], f1 = feats[e + 1], f2 = feats[e + 2], f3 = feats[e + 3];
            int s0 = srcs[e], s1 = srcs[e + 1], s2 = srcs[e + 2], s3 = srcs[e + 3];
            int seg0 = __popcll(__ballot(f0 > bpl));
            int seg1 = __popcll(__ballot(f1 > bpl));
            int seg2 = __popcll(__ballot(f2 > bpl));
            int seg3 = __popcll(__ballot(f3 > bpl));
            float g0 = G[(size_t)s0 * 64 + lane];
            float g1 = G[(size_t)s1 * 64 + lane];
            float g2 = G[(size_t)s2 * 64 + lane];
            float g3 = G[(size_t)s3 * 64 + lane];
            float h0 = fmaxf(g0 + fmaf(f0, sB[seg0 * 64 + lane], sA[seg0 * 64 + lane]), 0.f);
            float h1 = fmaxf(g1 + fmaf(f1, sB[seg1 * 64 + lane], sA[seg1 * 64 + lane]), 0.f);
            float h2 = fmaxf(g2 + fmaf(f2, sB[seg2 * 64 + lane], sA[seg2 * 64 + lane]), 0.f);
            float h3 = fmaxf(g3 + fmaf(f3, sB[seg3 * 64 + lane], sA[seg3 * 64 + lane]), 0.f);
            float m0 = b2v, m1 = b2v, m2 = b2v, m3 = b2v;
#pragma unroll
            for (int k = 0; k < 64; ++k) {
                m0 = fmaf(readlane_f(h0, k), w2c[k], m0);
                m1 = fmaf(readlane_f(h1, k), w2c[k], m1);
                m2 = fmaf(readlane_f(h2, k), w2c[k], m2);
                m3 = fmaf(readlane_f(h3, k), w2c[k], m3);
            }
            acc += fmaxf(m0, 0.f) + fmaxf(m1, 0.f) + fmaxf(m2, 0.f) + fmaxf(m3, 0.f);
        }
        for (; e < end; ++e) {
            float f0 = feats[e];
            int s0 = srcs[e];
            int seg0 = __popcll(__ballot(f0 > bpl));
            float g0 = G[(size_t)s0 * 64 + lane];
            float h0 = fmaxf(g0 + fmaf(f0, sB[seg0 * 64 + lane], sA[seg0 * 64 + lane]), 0.f);
            float m0 = b2v;
#pragma unroll
            for (int k = 0; k < 64; ++k) m0 = fmaf(readlane_f(h0, k), w2c[k], m0);
            acc += fmaxf(m0, 0.f);
        }
        float inv = 1.f / fmaxf((float)(end - beg), 1.f);
        Agg[(size_t)n * 64 + lane] = acc * inv;
    }
}

// head: t = relu(Hc@W1 + b1); pred[c] = sum_j t[j]*W2[j,c] + b2[c]; out = 2pi*sigmoid(pred)
__global__ __launch_bounds__(256, 2)
void head_kernel(const float* __restrict__ Hc, const float* __restrict__ W1,
                 const float* __restrict__ b1, const float* __restrict__ W2,
                 const float* __restrict__ b2, float* __restrict__ out, int N) {
    int lane = threadIdx.x & 63;
    float wcol[64];
#pragma unroll
    for (int k = 0; k < 64; ++k) wcol[k] = W1[k * 64 + lane];
    float bv = b1[lane];
    float w2c0 = W2[lane * 3 + 0], w2c1 = W2[lane * 3 + 1], w2c2 = W2[lane * 3 + 2];
    float b20 = b2[0], b21 = b2[1], b22 = b2[2];
    int wid = (blockIdx.x * blockDim.x + threadIdx.x) >> 6;
    int nw = (gridDim.x * blockDim.x) >> 6;
    const float TWO_PI = 6.283185307179586f;
    for (int n = wid; n < N; n += nw) {
        float x = Hc[(size_t)n * 64 + lane];
        float t = bv;
#pragma unroll
        for (int k = 0; k < 64; ++k) t = fmaf(readlane_f(x, k), wcol[k], t);
        t = fmaxf(t, 0.f);
        float p0 = t * w2c0, p1 = t * w2c1, p2 = t * w2c2;
#pragma unroll
        for (int off = 32; off > 0; off >>= 1) {
            p0 += __shfl_xor(p0, off);
            p1 += __shfl_xor(p1, off);
            p2 += __shfl_xor(p2, off);
        }
        if (lane == 0) {
            float v0 = p0 + b20, v1 = p1 + b21, v2 = p2 + b22;
            out[n * 3 + 0] = TWO_PI / (1.f + expf(-v0));
            out[n * 3 + 1] = TWO_PI / (1.f + expf(-v1));
            out[n * 3 + 2] = TWO_PI / (1.f + expf(-v2));
        }
    }
}

extern "C" void kernel_launch(void* const* d_in, const int* in_sizes, int n_in,
                              void* d_out, int out_size, void* d_ws, size_t ws_size,
                              hipStream_t stream) {
    const float* nf    = (const float*)d_in[0];
    const int*   ei    = (const int*)d_in[1];
    const float* ef    = (const float*)d_in[2];
    const float* encW1 = (const float*)d_in[3];
    const float* encb1 = (const float*)d_in[4];
    const float* encW2 = (const float*)d_in[5];
    const float* encb2 = (const float*)d_in[6];
    const float* eeW   = (const float*)d_in[7];
    const float* eeb   = (const float*)d_in[8];
    const float* mW1   = (const float*)d_in[9];
    const float* mb1   = (const float*)d_in[10];
    const float* mW2   = (const float*)d_in[11];
    const float* mb2   = (const float*)d_in[12];
    const float* uW1   = (const float*)d_in[13];
    const float* ub1   = (const float*)d_in[14];
    const float* uW2   = (const float*)d_in[15];
    const float* ub2   = (const float*)d_in[16];
    const float* oW1   = (const float*)d_in[17];
    const float* ob1   = (const float*)d_in[18];
    const float* oW2   = (const float*)d_in[19];
    const float* ob2   = (const float*)d_in[20];
    float* out = (float*)d_out;

    int N = in_sizes[0] / 5;   // 50000
    int E = in_sizes[2];       // 800000
    size_t N64 = (size_t)N * 64;

    float* ws  = (float*)d_ws;
    float* h   = ws;
    float* hn  = ws + N64;
    float* g   = ws + 2 * N64;   // also reused as t1 in the update phase
    float* agg = ws + 3 * N64;
    int* rowstart = (int*)(ws + 4 * N64);  // N+1
    int* cursor   = rowstart + (N + 1);    // N
    int* dcnt     = cursor + N;            // N
    int* srcs     = dcnt + N;              // E
    float* feats  = (float*)(srcs + E);    // E
    float* bp     = feats + E;             // 64
    float* Atab   = bp + 64;               // 3*65*64
    float* Btab   = Atab + 3 * 65 * 64;    // 3*65*64

    // piecewise-linear tables for the edge-encoder->W1b path (fixed inputs)
    bp_kernel<<<1, 64, 0, stream>>>(eeW, eeb, bp);
    tab_kernel<<<195, 64, 0, stream>>>(eeW, eeb, mW1, bp, Atab, Btab);

    // node encoder
    enc1_kernel<<<512, 256, 0, stream>>>(nf, encW1, encb1, g, N);
    gemm64_kernel<0, 1, 1><<<1024, 256, 0, stream>>>(g, encW2, encb2, nullptr, h, N);

    // CSR build (dst-sorted edge list), reused by all 3 layers
    zero_int_kernel<<<256, 256, 0, stream>>>(dcnt, N);
    hist_kernel<<<(E + 255) / 256, 256, 0, stream>>>(ei, dcnt, E);
    scan_kernel<<<1, 1024, 0, stream>>>(dcnt, rowstart, cursor, N);
    fill_kernel<<<(E + 255) / 256, 256, 0, stream>>>(ei, ef, cursor, srcs, feats, E);

    for (int l = 0; l < 3; ++l) {
        const float* W1a = mW1 + (size_t)l * 128 * 64;
        const float* b1  = mb1 + l * 64;
        const float* W2  = mW2 + (size_t)l * 64 * 64;
        const float* b2  = mb2 + l * 64;
        // g = h @ W1a + b1 (src-side half of message concat-matmul, per node)
        gemm64_kernel<0, 0, 1><<<1024, 256, 0, stream>>>(h, W1a, b1, nullptr, g, N);
        msg_gather2_kernel<<<1024, 256, 0, stream>>>(g, rowstart, srcs, feats, bp,
                                                     Atab + (size_t)l * 65 * 64,
                                                     Btab + (size_t)l * 65 * 64,
                                                     W2, b2, agg, N);
        const float* U1a = uW1 + (size_t)l * 128 * 64;
        const float* U1b = U1a + 64 * 64;
        const float* v1  = ub1 + l * 64;
        const float* U2  = uW2 + (size_t)l * 64 * 64;
        const float* v2  = ub2 + l * 64;
        // t1 (=g) = h@U1a + b1 ; agg = relu(t1 + agg@U1b) ; hn = relu(agg@U2 + b2)
        gemm64_kernel<0, 0, 1><<<1024, 256, 0, stream>>>(h, U1a, v1, nullptr, g, N);
        gemm64_kernel<1, 1, 0><<<1024, 256, 0, stream>>>(agg, U1b, nullptr, g, agg, N);
        gemm64_kernel<0, 1, 1><<<1024, 256, 0, stream>>>(agg, U2, v2, nullptr, hn, N);
        float* tmp = h; h = hn; hn = tmp;
    }

    head_kernel<<<1024, 256, 0, stream>>>(h, oW1, ob1, oW2, ob2, out, N);
}

// Round 5
// 960.031 us; speedup vs baseline: 4.1774x; 1.2422x over previous
//
#include <hip/hip_runtime.h>
#include <math.h>

typedef short bf16x8 __attribute__((ext_vector_type(8)));
typedef float f32x4 __attribute__((ext_vector_type(4)));

union ABFrag { int i[4]; bf16x8 v; };

__device__ __forceinline__ float readlane_f(float v, int l) {
    return __uint_as_float(__builtin_amdgcn_readlane(__float_as_uint(v), l));
}

// pack two f32 -> two bf16 (RNE) in one u32 (lo = a, hi = b)
__device__ __forceinline__ int pack2bf(float a, float b) {
    unsigned ua = __float_as_uint(a);
    unsigned ub = __float_as_uint(b);
    ua = (ua + 0x7FFFu + ((ua >> 16) & 1u)) >> 16;
    ub = (ub + 0x7FFFu + ((ub >> 16) & 1u)) & 0xFFFF0000u;
    return (int)(ua | ub);
}

__global__ void zero_int_kernel(int* __restrict__ p, int n) {
    int i = blockIdx.x * blockDim.x + threadIdx.x;
    int stride = gridDim.x * blockDim.x;
    for (; i < n; i += stride) p[i] = 0;
}

__global__ void zero_f4_kernel(float4* __restrict__ p, int n4) {
    int i = blockIdx.x * blockDim.x + threadIdx.x;
    int stride = gridDim.x * blockDim.x;
    float4 z = {0.f, 0.f, 0.f, 0.f};
    for (; i < n4; i += stride) p[i] = z;
}

__global__ void hist_kernel(const int* __restrict__ EI, int* __restrict__ cnt, int E) {
    int e = blockIdx.x * blockDim.x + threadIdx.x;
    if (e < E) atomicAdd(&cnt[EI[E + e]], 1);
}

// single-block exclusive scan over cnt[N] -> rowstart[N+1], cursor[N]
__global__ __launch_bounds__(1024)
void scan_kernel(const int* __restrict__ cnt, int* __restrict__ rowstart,
                 int* __restrict__ cursor, int N) {
    __shared__ int sbuf[1024];
    __shared__ int soff;
    int tid = threadIdx.x;
    if (tid == 0) soff = 0;
    __syncthreads();
    for (int base = 0; base < N; base += 1024) {
        int i = base + tid;
        int v = (i < N) ? cnt[i] : 0;
        sbuf[tid] = v;
        __syncthreads();
#pragma unroll
        for (int d = 1; d < 1024; d <<= 1) {
            int t = (tid >= d) ? sbuf[tid - d] : 0;
            __syncthreads();
            sbuf[tid] += t;
            __syncthreads();
        }
        int incl = sbuf[tid];
        int total = sbuf[1023];
        int my = soff + incl - v;
        if (i < N) { rowstart[i] = my; cursor[i] = my; }
        __syncthreads();
        if (tid == 0) soff += total;
        __syncthreads();
    }
    if (tid == 0) rowstart[N] = soff;
}

__global__ void inv_kernel(const int* __restrict__ rowstart, float* __restrict__ inv, int N) {
    int i = blockIdx.x * blockDim.x + threadIdx.x;
    if (i < N) {
        int d = rowstart[i + 1] - rowstart[i];
        inv[i] = 1.f / ((d > 1) ? (float)d : 1.f);
    }
}

// scatter edges into dst-sorted slots; also precompute seg (piecewise-linear segment of f)
__global__ __launch_bounds__(256)
void fill_kernel(const int* __restrict__ EI, const float* __restrict__ EF,
                 const float* __restrict__ bp, int* __restrict__ cursor,
                 int* __restrict__ srcs, float* __restrict__ feats,
                 int* __restrict__ dsts, unsigned char* __restrict__ seg, int E) {
    __shared__ float sbp[64];
    if (threadIdx.x < 64) sbp[threadIdx.x] = bp[threadIdx.x];
    __syncthreads();
    int e = blockIdx.x * blockDim.x + threadIdx.x;
    if (e < E) {
        int dst = EI[E + e];
        int slot = atomicAdd(&cursor[dst], 1);
        float f = EF[e];
        int sg = 0;
#pragma unroll
        for (int st = 32; st >= 1; st >>= 1)
            if (sg + st <= 64 && sbp[sg + st - 1] < f) sg += st;
        srcs[slot] = EI[e];
        feats[slot] = f;
        dsts[slot] = dst;
        seg[slot] = (unsigned char)sg;
    }
}

// sorted breakpoints of f -> relu(f*eW+eB): t_k = -eB_k/eW_k (eW_k != 0)
__global__ __launch_bounds__(64)
void bp_kernel(const float* __restrict__ eW, const float* __restrict__ eB,
               float* __restrict__ bp) {
    int lane = threadIdx.x;
    float w = eW[lane], b = eB[lane];
    float t = (w != 0.f) ? (-b / w) : 1e30f;
    __shared__ float sbp[64];
    int rank = 0;
    for (int j = 0; j < 64; ++j) {
        float tj = readlane_f(t, j);
        rank += (tj < t) || (tj == t && j < lane);
    }
    sbp[rank] = t;
    __syncthreads();
    bp[lane] = sbp[lane];
}

// per (layer, segment): A[j] = sum_{k active} eB_k*W1b[k][j], B[j] = sum eW_k*W1b[k][j]
__global__ __launch_bounds__(64)
void tab_kernel(const float* __restrict__ eW, const float* __restrict__ eB,
                const float* __restrict__ mW1, const float* __restrict__ bp,
                float* __restrict__ Atab, float* __restrict__ Btab) {
    int s = blockIdx.x % 65;
    int l = blockIdx.x / 65;
    int j = threadIdx.x;
    float lo = (s == 0) ? 0.f : bp[s - 1];
    float hi = (s == 64) ? 0.f : bp[s];
    float rep;
    if (s == 0) rep = hi - fmaxf(1.f, fabsf(hi));
    else if (s == 64) rep = lo + fmaxf(1.f, fabsf(lo));
    else rep = 0.5f * (lo + hi);
    const float* W1b = mW1 + (size_t)l * 128 * 64 + 64 * 64;
    float A = 0.f, B = 0.f;
    for (int k = 0; k < 64; ++k) {
        float w = eW[k], b = eB[k];
        if (fmaf(rep, w, b) > 0.f) {
            float wv = W1b[k * 64 + j];
            A = fmaf(b, wv, A);
            B = fmaf(w, wv, B);
        }
    }
    Atab[((size_t)l * 65 + s) * 64 + j] = A;
    Btab[((size_t)l * 65 + s) * 64 + j] = B;
}

// first encoder layer: Y[n,j] = relu(b[j] + sum_{k<5} NF[n,k]*W[k,j])
__global__ __launch_bounds__(256)
void enc1_kernel(const float* __restrict__ NF, const float* __restrict__ W,
                 const float* __restrict__ b, float* __restrict__ Y, int N) {
    int lane = threadIdx.x & 63;
    float w0 = W[0 * 64 + lane], w1 = W[1 * 64 + lane], w2 = W[2 * 64 + lane];
    float w3 = W[3 * 64 + lane], w4 = W[4 * 64 + lane];
    float bv = b[lane];
    int wid = (blockIdx.x * blockDim.x + threadIdx.x) >> 6;
    int nw = (gridDim.x * blockDim.x) >> 6;
    for (int n = wid; n < N; n += nw) {
        float x = (lane < 5) ? NF[n * 5 + lane] : 0.f;
        float acc = bv;
        acc = fmaf(readlane_f(x, 0), w0, acc);
        acc = fmaf(readlane_f(x, 1), w1, acc);
        acc = fmaf(readlane_f(x, 2), w2, acc);
        acc = fmaf(readlane_f(x, 3), w3, acc);
        acc = fmaf(readlane_f(x, 4), w4, acc);
        Y[n * 64 + lane] = fmaxf(acc, 0.f);
    }
}

// Y[n,:] = act( Z?[n,:] + (sc?[n]*X[n,:])@W + b? ); weights staged in LDS (broadcast reads)
template <int HAS_Z, int RELU, int HAS_B, int HAS_SC>
__global__ __launch_bounds__(256, 2)
void gemm64_kernel(const float* __restrict__ X, const float* __restrict__ W,
                   const float* __restrict__ b, const float* __restrict__ Z,
                   const float* __restrict__ sc, float* __restrict__ Y, int N) {
    __shared__ float sW[64 * 64];
    int tid = threadIdx.x;
    for (int i = tid; i < 64 * 64; i += 256) sW[i] = W[i];
    __syncthreads();
    int lane = tid & 63;
    float bv = HAS_B ? b[lane] : 0.f;
    int wid = (blockIdx.x * blockDim.x + tid) >> 6;
    int nw = (gridDim.x * blockDim.x) >> 6;
    for (int n0 = wid * 4; n0 < N; n0 += nw * 4) {
        if (n0 + 3 < N) {
            float x0 = X[(size_t)n0 * 64 + lane];
            float x1 = X[(size_t)(n0 + 1) * 64 + lane];
            float x2 = X[(size_t)(n0 + 2) * 64 + lane];
            float x3 = X[(size_t)(n0 + 3) * 64 + lane];
            if (HAS_SC) {
                x0 *= sc[n0]; x1 *= sc[n0 + 1]; x2 *= sc[n0 + 2]; x3 *= sc[n0 + 3];
            }
            float a0 = bv, a1 = bv, a2 = bv, a3 = bv;
            if (HAS_Z) {
                a0 += Z[(size_t)n0 * 64 + lane];
                a1 += Z[(size_t)(n0 + 1) * 64 + lane];
                a2 += Z[(size_t)(n0 + 2) * 64 + lane];
                a3 += Z[(size_t)(n0 + 3) * 64 + lane];
            }
#pragma unroll
            for (int k = 0; k < 64; ++k) {
                float wk = sW[(k << 6) + lane];
                a0 = fmaf(readlane_f(x0, k), wk, a0);
                a1 = fmaf(readlane_f(x1, k), wk, a1);
                a2 = fmaf(readlane_f(x2, k), wk, a2);
                a3 = fmaf(readlane_f(x3, k), wk, a3);
            }
            if (RELU) {
                a0 = fmaxf(a0, 0.f); a1 = fmaxf(a1, 0.f);
                a2 = fmaxf(a2, 0.f); a3 = fmaxf(a3, 0.f);
            }
            Y[(size_t)n0 * 64 + lane] = a0;
            Y[(size_t)(n0 + 1) * 64 + lane] = a1;
            Y[(size_t)(n0 + 2) * 64 + lane] = a2;
            Y[(size_t)(n0 + 3) * 64 + lane] = a3;
        } else {
            for (int n = n0; n < N; ++n) {
                float x0 = X[(size_t)n * 64 + lane];
                if (HAS_SC) x0 *= sc[n];
                float a0 = bv;
                if (HAS_Z) a0 += Z[(size_t)n * 64 + lane];
#pragma unroll
                for (int k = 0; k < 64; ++k)
                    a0 = fmaf(readlane_f(x0, k), sW[(k << 6) + lane], a0);
                if (RELU) a0 = fmaxf(a0, 0.f);
                Y[(size_t)n * 64 + lane] = a0;
            }
        }
    }
}

// MFMA message kernel: one 16-edge tile per wave iteration over the dst-sorted edge list.
// h[row] = relu(G[src] + ce(f)), ce via LDS piecewise-linear table (XOR-swizzled);
// messages = relu(h @ W2 + b2) via 8x mfma_f32_16x16x32_bf16; run-length segmented
// atomicAdd into Agg (sums; mean folded into consumer via inv[]).
__global__ __launch_bounds__(256, 2)
void msg_mfma_kernel(const float* __restrict__ G, const int* __restrict__ srcs,
                     const float* __restrict__ feats, const int* __restrict__ dsts,
                     const unsigned char* __restrict__ seg,
                     const float* __restrict__ Atab, const float* __restrict__ Btab,
                     const float* __restrict__ W2, const float* __restrict__ b2p,
                     float* __restrict__ Agg, int E) {
    __shared__ float sA[65 * 64], sB[65 * 64];
    int tid = threadIdx.x;
    for (int i = tid; i < 65 * 64; i += 256) {
        int sgi = i >> 6, c = i & 63;
        int pos = (sgi << 6) + ((((c >> 2) ^ (sgi & 7)) << 2) | (c & 3));
        sA[pos] = Atab[i];
        sB[pos] = Btab[i];
    }
    int lane = tid & 63;
    int n15 = lane & 15;
    int kg = lane >> 4;   // 0..3: A col-block / B k-group / C row-group

    // B fragments of W2 (bf16), register-resident: bf[nt][kt], k = kt*32 + kg*8 + j
    ABFrag bf[4][2];
#pragma unroll
    for (int nt = 0; nt < 4; ++nt)
#pragma unroll
        for (int kt = 0; kt < 2; ++kt)
#pragma unroll
            for (int jj = 0; jj < 4; ++jj) {
                int k0 = kt * 32 + kg * 8 + 2 * jj;
                float w0 = W2[(size_t)k0 * 64 + nt * 16 + n15];
                float w1 = W2[(size_t)(k0 + 1) * 64 + nt * 16 + n15];
                bf[nt][kt].i[jj] = pack2bf(w0, w1);
            }
    float b2v[4];
#pragma unroll
    for (int nt = 0; nt < 4; ++nt) b2v[nt] = b2p[nt * 16 + n15];
    __syncthreads();

    int wid = (blockIdx.x * blockDim.x + tid) >> 6;
    int nw = (gridDim.x * blockDim.x) >> 6;
    int nTiles = (E + 15) >> 4;
    for (int t = wid; t < nTiles; t += nw) {
        int e0 = t << 4;
        int eRow = e0 + n15;
        int ec = (eRow < E) ? eRow : (E - 1);
        float f = feats[ec];
        int src = srcs[ec];
        int sg = (int)seg[ec];
        int sgb = sg << 6;
        int sx = sg & 7;
        const float* gp = G + (size_t)src * 64 + kg * 8;
        float4 g0 = *(const float4*)(gp);
        float4 g1 = *(const float4*)(gp + 4);
        float4 g2 = *(const float4*)(gp + 32);
        float4 g3 = *(const float4*)(gp + 36);
        int q0 = (kg * 2) ^ sx;
        int q1 = (kg * 2 + 1) ^ sx;
        int q2 = (kg * 2 + 8) ^ sx;
        int q3 = (kg * 2 + 9) ^ sx;
        float4 ta0 = *(const float4*)&sA[sgb + (q0 << 2)];
        float4 tb0 = *(const float4*)&sB[sgb + (q0 << 2)];
        float4 ta1 = *(const float4*)&sA[sgb + (q1 << 2)];
        float4 tb1 = *(const float4*)&sB[sgb + (q1 << 2)];
        float4 ta2 = *(const float4*)&sA[sgb + (q2 << 2)];
        float4 tb2 = *(const float4*)&sB[sgb + (q2 << 2)];
        float4 ta3 = *(const float4*)&sA[sgb + (q3 << 2)];
        float4 tb3 = *(const float4*)&sB[sgb + (q3 << 2)];
        float h0 = fmaxf(g0.x + fmaf(f, tb0.x, ta0.x), 0.f);
        float h1 = fmaxf(g0.y + fmaf(f, tb0.y, ta0.y), 0.f);
        float h2 = fmaxf(g0.z + fmaf(f, tb0.z, ta0.z), 0.f);
        float h3 = fmaxf(g0.w + fmaf(f, tb0.w, ta0.w), 0.f);
        float h4 = fmaxf(g1.x + fmaf(f, tb1.x, ta1.x), 0.f);
        float h5 = fmaxf(g1.y + fmaf(f, tb1.y, ta1.y), 0.f);
        float h6 = fmaxf(g1.z + fmaf(f, tb1.z, ta1.z), 0.f);
        float h7 = fmaxf(g1.w + fmaf(f, tb1.w, ta1.w), 0.f);
        float h8 = fmaxf(g2.x + fmaf(f, tb2.x, ta2.x), 0.f);
        float h9 = fmaxf(g2.y + fmaf(f, tb2.y, ta2.y), 0.f);
        float h10 = fmaxf(g2.z + fmaf(f, tb2.z, ta2.z), 0.f);
        float h11 = fmaxf(g2.w + fmaf(f, tb2.w, ta2.w), 0.f);
        float h12 = fmaxf(g3.x + fmaf(f, tb3.x, ta3.x), 0.f);
        float h13 = fmaxf(g3.y + fmaf(f, tb3.y, ta3.y), 0.f);
        float h14 = fmaxf(g3.z + fmaf(f, tb3.z, ta3.z), 0.f);
        float h15 = fmaxf(g3.w + fmaf(f, tb3.w, ta3.w), 0.f);
        ABFrag A0, A1;
        A0.i[0] = pack2bf(h0, h1);
        A0.i[1] = pack2bf(h2, h3);
        A0.i[2] = pack2bf(h4, h5);
        A0.i[3] = pack2bf(h6, h7);
        A1.i[0] = pack2bf(h8, h9);
        A1.i[1] = pack2bf(h10, h11);
        A1.i[2] = pack2bf(h12, h13);
        A1.i[3] = pack2bf(h14, h15);
        f32x4 acc[4];
#pragma unroll
        for (int nt = 0; nt < 4; ++nt) {
            acc[nt][0] = b2v[nt]; acc[nt][1] = b2v[nt];
            acc[nt][2] = b2v[nt]; acc[nt][3] = b2v[nt];
        }
#pragma unroll
        for (int nt = 0; nt < 4; ++nt) {
            acc[nt] = __builtin_amdgcn_mfma_f32_16x16x32_bf16(A0.v, bf[nt][0].v, acc[nt], 0, 0, 0);
            acc[nt] = __builtin_amdgcn_mfma_f32_16x16x32_bf16(A1.v, bf[nt][1].v, acc[nt], 0, 0, 0);
        }
        // segmented reduction over this lane's 4 rows (edges e0+kg*4 .. +3), dst-sorted
        int R0 = e0 + kg * 4;
        const int4 dd = *(const int4*)(dsts + R0);   // padded allocation
        int d0 = dd.x, d1 = dd.y, d2 = dd.z, d3 = dd.w;
#pragma unroll
        for (int nt = 0; nt < 4; ++nt) {
            int col = nt * 16 + n15;
            float m0 = fmaxf(acc[nt][0], 0.f);
            float m1 = fmaxf(acc[nt][1], 0.f);
            float m2 = fmaxf(acc[nt][2], 0.f);
            float m3 = fmaxf(acc[nt][3], 0.f);
            float s = 0.f;
            int dp = -1;
            if (R0 < E) { s = m0; dp = d0; }
            if (R0 + 1 < E) {
                if (d1 == dp) s += m1;
                else { if (dp >= 0) atomicAdd(&Agg[(size_t)dp * 64 + col], s); s = m1; dp = d1; }
            }
            if (R0 + 2 < E) {
                if (d2 == dp) s += m2;
                else { if (dp >= 0) atomicAdd(&Agg[(size_t)dp * 64 + col], s); s = m2; dp = d2; }
            }
            if (R0 + 3 < E) {
                if (d3 == dp) s += m3;
                else { if (dp >= 0) atomicAdd(&Agg[(size_t)dp * 64 + col], s); s = m3; dp = d3; }
            }
            if (dp >= 0) atomicAdd(&Agg[(size_t)dp * 64 + col], s);
        }
    }
}

// head: t = relu(Hc@W1 + b1); pred[c] = sum_j t[j]*W2[j,c] + b2[c]; out = 2pi*sigmoid(pred)
__global__ __launch_bounds__(256, 2)
void head_kernel(const float* __restrict__ Hc, const float* __restrict__ W1,
                 const float* __restrict__ b1, const float* __restrict__ W2,
                 const float* __restrict__ b2, float* __restrict__ out, int N) {
    __shared__ float sW[64 * 64];
    int tid = threadIdx.x;
    for (int i = tid; i < 64 * 64; i += 256) sW[i] = W1[i];
    __syncthreads();
    int lane = tid & 63;
    float bv = b1[lane];
    float w2c0 = W2[lane * 3 + 0], w2c1 = W2[lane * 3 + 1], w2c2 = W2[lane * 3 + 2];
    float b20 = b2[0], b21 = b2[1], b22 = b2[2];
    int wid = (blockIdx.x * blockDim.x + tid) >> 6;
    int nw = (gridDim.x * blockDim.x) >> 6;
    const float TWO_PI = 6.283185307179586f;
    for (int n = wid; n < N; n += nw) {
        float x = Hc[(size_t)n * 64 + lane];
        float t = bv;
#pragma unroll
        for (int k = 0; k < 64; ++k) t = fmaf(readlane_f(x, k), sW[(k << 6) + lane], t);
        t = fmaxf(t, 0.f);
        float p0 = t * w2c0, p1 = t * w2c1, p2 = t * w2c2;
#pragma unroll
        for (int off = 32; off > 0; off >>= 1) {
            p0 += __shfl_xor(p0, off);
            p1 += __shfl_xor(p1, off);
            p2 += __shfl_xor(p2, off);
        }
        if (lane == 0) {
            float v0 = p0 + b20, v1 = p1 + b21, v2 = p2 + b22;
            out[n * 3 + 0] = TWO_PI / (1.f + expf(-v0));
            out[n * 3 + 1] = TWO_PI / (1.f + expf(-v1));
            out[n * 3 + 2] = TWO_PI / (1.f + expf(-v2));
        }
    }
}

extern "C" void kernel_launch(void* const* d_in, const int* in_sizes, int n_in,
                              void* d_out, int out_size, void* d_ws, size_t ws_size,
                              hipStream_t stream) {
    const float* nf    = (const float*)d_in[0];
    const int*   ei    = (const int*)d_in[1];
    const float* ef    = (const float*)d_in[2];
    const float* encW1 = (const float*)d_in[3];
    const float* encb1 = (const float*)d_in[4];
    const float* encW2 = (const float*)d_in[5];
    const float* encb2 = (const float*)d_in[6];
    const float* eeW   = (const float*)d_in[7];
    const float* eeb   = (const float*)d_in[8];
    const float* mW1   = (const float*)d_in[9];
    const float* mb1   = (const float*)d_in[10];
    const float* mW2   = (const float*)d_in[11];
    const float* mb2   = (const float*)d_in[12];
    const float* uW1   = (const float*)d_in[13];
    const float* ub1   = (const float*)d_in[14];
    const float* uW2   = (const float*)d_in[15];
    const float* ub2   = (const float*)d_in[16];
    const float* oW1   = (const float*)d_in[17];
    const float* ob1   = (const float*)d_in[18];
    const float* oW2   = (const float*)d_in[19];
    const float* ob2   = (const float*)d_in[20];
    float* out = (float*)d_out;

    int N = in_sizes[0] / 5;   // 50000
    int E = in_sizes[2];       // 800000
    size_t N64 = (size_t)N * 64;
    size_t Np = (size_t)((N + 3) & ~3);
    size_t Ep = (size_t)((E + 3) & ~3);

    float* ws   = (float*)d_ws;
    float* h    = ws;
    float* g    = ws + N64;
    float* agg  = ws + 2 * N64;
    float* feats = ws + 3 * N64;            // Ep
    float* inv   = feats + Ep;              // Np
    float* bp    = inv + Np;                // 64
    float* Atab  = bp + 64;                 // 3*65*64
    float* Btab  = Atab + 3 * 65 * 64;      // 3*65*64
    int* rowstart = (int*)(Btab + 3 * 65 * 64);  // Np+4
    int* cursor   = rowstart + Np + 4;      // Np
    int* dcnt     = cursor + Np;            // Np
    int* srcs     = dcnt + Np;              // Ep
    int* dsts     = srcs + Ep;              // Ep + 16 (padded for int4 tail reads)
    unsigned char* seg = (unsigned char*)(dsts + Ep + 16);  // Ep + 16

    // piecewise-linear tables for the edge-encoder->W1b path (fixed inputs)
    bp_kernel<<<1, 64, 0, stream>>>(eeW, eeb, bp);
    tab_kernel<<<195, 64, 0, stream>>>(eeW, eeb, mW1, bp, Atab, Btab);

    // node encoder
    enc1_kernel<<<512, 256, 0, stream>>>(nf, encW1, encb1, g, N);
    gemm64_kernel<0, 1, 1, 0><<<1024, 256, 0, stream>>>(g, encW2, encb2, nullptr, nullptr, h, N);

    // CSR build (dst-sorted edge list) + per-edge segment + 1/deg; reused by all 3 layers
    zero_int_kernel<<<256, 256, 0, stream>>>(dcnt, N);
    hist_kernel<<<(E + 255) / 256, 256, 0, stream>>>(ei, dcnt, E);
    scan_kernel<<<1, 1024, 0, stream>>>(dcnt, rowstart, cursor, N);
    inv_kernel<<<(N + 255) / 256, 256, 0, stream>>>(rowstart, inv, N);
    fill_kernel<<<(E + 255) / 256, 256, 0, stream>>>(ei, ef, bp, cursor, srcs, feats, dsts, seg, E);

    for (int l = 0; l < 3; ++l) {
        const float* W1a = mW1 + (size_t)l * 128 * 64;
        const float* b1  = mb1 + l * 64;
        const float* W2  = mW2 + (size_t)l * 64 * 64;
        const float* b2  = mb2 + l * 64;
        // g = h @ W1a + b1 (src-side half of message concat-matmul, per node)
        gemm64_kernel<0, 0, 1, 0><<<1024, 256, 0, stream>>>(h, W1a, b1, nullptr, nullptr, g, N);
        zero_f4_kernel<<<1024, 256, 0, stream>>>((float4*)agg, (int)(N64 / 4));
        msg_mfma_kernel<<<1024, 256, 0, stream>>>(g, srcs, feats, dsts, seg,
                                                  Atab + (size_t)l * 65 * 64,
                                                  Btab + (size_t)l * 65 * 64,
                                                  W2, b2, agg, E);
        const float* U1a = uW1 + (size_t)l * 128 * 64;
        const float* U1b = U1a + 64 * 64;
        const float* v1  = ub1 + l * 64;
        const float* U2  = uW2 + (size_t)l * 64 * 64;
        const float* v2  = ub2 + l * 64;
        // g = h@U1a + b1 ; agg = relu(g + (agg*inv)@U1b) ; g = relu(agg@U2 + b2) -> new h
        gemm64_kernel<0, 0, 1, 0><<<1024, 256, 0, stream>>>(h, U1a, v1, nullptr, nullptr, g, N);
        gemm64_kernel<1, 1, 0, 1><<<1024, 256, 0, stream>>>(agg, U1b, nullptr, g, inv, agg, N);
        gemm64_kernel<0, 1, 1, 0><<<1024, 256, 0, stream>>>(agg, U2, v2, nullptr, nullptr, g, N);
        float* tmp = h; h = g; g = tmp;
    }

    head_kernel<<<1024, 256, 0, stream>>>(h, oW1, ob1, oW2, ob2, out, N);
}

// Round 6
// 477.979 us; speedup vs baseline: 8.3903x; 2.0085x over previous
//
#include <hip/hip_runtime.h>
#include <math.h>

typedef short bf16x8 __attribute__((ext_vector_type(8)));
typedef float f32x4 __attribute__((ext_vector_type(4)));

union ABFrag { int i[4]; bf16x8 v; };

__device__ __forceinline__ float readlane_f(float v, int l) {
    return __uint_as_float(__builtin_amdgcn_readlane(__float_as_uint(v), l));
}

// pack two f32 -> two bf16 (RNE) in one u32 (lo = a, hi = b)
__device__ __forceinline__ int pack2bf(float a, float b) {
    unsigned ua = __float_as_uint(a);
    unsigned ub = __float_as_uint(b);
    ua = (ua + 0x7FFFu + ((ua >> 16) & 1u)) >> 16;
    ub = (ub + 0x7FFFu + ((ub >> 16) & 1u)) & 0xFFFF0000u;
    return (int)(ua | ub);
}
__device__ __forceinline__ float bflo(int d) { return __uint_as_float((unsigned)d << 16); }
__device__ __forceinline__ float bfhi(int d) { return __uint_as_float((unsigned)d & 0xFFFF0000u); }

__global__ void zero_int_kernel(int* __restrict__ p, int n) {
    int i = blockIdx.x * blockDim.x + threadIdx.x;
    int stride = gridDim.x * blockDim.x;
    for (; i < n; i += stride) p[i] = 0;
}

__global__ void hist_kernel(const int* __restrict__ EI, int* __restrict__ cnt, int E) {
    int e = blockIdx.x * blockDim.x + threadIdx.x;
    if (e < E) atomicAdd(&cnt[EI[E + e]], 1);
}

// single-block chunked exclusive scan: cnt[N] -> rowstart[N+1], cursor[N]
__global__ __launch_bounds__(1024)
void scan_kernel(const int* __restrict__ cnt, int* __restrict__ rowstart,
                 int* __restrict__ cursor, int N) {
    __shared__ int sbuf[1024];
    int tid = threadIdx.x;
    int per = (N + 1023) >> 10;
    int lo = tid * per;
    int hi = lo + per; if (hi > N) hi = N;
    int s = 0;
    for (int i = lo; i < hi; ++i) s += cnt[i];
    sbuf[tid] = s;
    __syncthreads();
#pragma unroll
    for (int d = 1; d < 1024; d <<= 1) {
        int t = (tid >= d) ? sbuf[tid - d] : 0;
        __syncthreads();
        sbuf[tid] += t;
        __syncthreads();
    }
    int run = sbuf[tid] - s;   // exclusive prefix for this chunk
    for (int i = lo; i < hi; ++i) {
        rowstart[i] = run;
        cursor[i] = run;
        run += cnt[i];
    }
    if (tid == 1023) rowstart[N] = sbuf[1023];
}

// scatter edges into dst-sorted slots; precompute piecewise-linear segment of f
__global__ __launch_bounds__(256)
void fill_kernel(const int* __restrict__ EI, const float* __restrict__ EF,
                 const float* __restrict__ bp, int* __restrict__ cursor,
                 int* __restrict__ srcs, float* __restrict__ feats,
                 unsigned char* __restrict__ seg, int E) {
    __shared__ float sbp[64];
    if (threadIdx.x < 64) sbp[threadIdx.x] = bp[threadIdx.x];
    __syncthreads();
    int e = blockIdx.x * blockDim.x + threadIdx.x;
    if (e < E) {
        int dst = EI[E + e];
        int slot = atomicAdd(&cursor[dst], 1);
        float f = EF[e];
        int sg = 0;
#pragma unroll
        for (int st = 32; st >= 1; st >>= 1)
            if (sg + st <= 64 && sbp[sg + st - 1] < f) sg += st;
        srcs[slot] = EI[e];
        feats[slot] = f;
        seg[slot] = (unsigned char)sg;
    }
}

// sorted breakpoints of f -> relu(f*eW+eB): t_k = -eB_k/eW_k (eW_k != 0)
__global__ __launch_bounds__(64)
void bp_kernel(const float* __restrict__ eW, const float* __restrict__ eB,
               float* __restrict__ bp) {
    int lane = threadIdx.x;
    float w = eW[lane], b = eB[lane];
    float t = (w != 0.f) ? (-b / w) : 1e30f;
    __shared__ float sbp[64];
    int rank = 0;
    for (int j = 0; j < 64; ++j) {
        float tj = readlane_f(t, j);
        rank += (tj < t) || (tj == t && j < lane);
    }
    sbp[rank] = t;
    __syncthreads();
    bp[lane] = sbp[lane];
}

// per (layer, segment): A[j] = sum_{k active} eB_k*W1b[k][j], B[j] = sum eW_k*W1b[k][j]
__global__ __launch_bounds__(64)
void tab_kernel(const float* __restrict__ eW, const float* __restrict__ eB,
                const float* __restrict__ mW1, const float* __restrict__ bp,
                float* __restrict__ Atab, float* __restrict__ Btab) {
    int s = blockIdx.x % 65;
    int l = blockIdx.x / 65;
    int j = threadIdx.x;
    float lo = (s == 0) ? 0.f : bp[s - 1];
    float hi = (s == 64) ? 0.f : bp[s];
    float rep;
    if (s == 0) rep = hi - fmaxf(1.f, fabsf(hi));
    else if (s == 64) rep = lo + fmaxf(1.f, fabsf(lo));
    else rep = 0.5f * (lo + hi);
    const float* W1b = mW1 + (size_t)l * 128 * 64 + 64 * 64;
    float A = 0.f, B = 0.f;
    for (int k = 0; k < 64; ++k) {
        float w = eW[k], b = eB[k];
        if (fmaf(rep, w, b) > 0.f) {
            float wv = W1b[k * 64 + j];
            A = fmaf(b, wv, A);
            B = fmaf(w, wv, B);
        }
    }
    Atab[((size_t)l * 65 + s) * 64 + j] = A;
    Btab[((size_t)l * 65 + s) * 64 + j] = B;
}

// first encoder layer: Y[n,j] = relu(b[j] + sum_{k<5} NF[n,k]*W[k,j])
__global__ __launch_bounds__(256)
void enc1_kernel(const float* __restrict__ NF, const float* __restrict__ W,
                 const float* __restrict__ b, float* __restrict__ Y, int N) {
    int lane = threadIdx.x & 63;
    float w0 = W[0 * 64 + lane], w1 = W[1 * 64 + lane], w2 = W[2 * 64 + lane];
    float w3 = W[3 * 64 + lane], w4 = W[4 * 64 + lane];
    float bv = b[lane];
    int wid = (blockIdx.x * blockDim.x + threadIdx.x) >> 6;
    int nw = (gridDim.x * blockDim.x) >> 6;
    for (int n = wid; n < N; n += nw) {
        float x = (lane < 5) ? NF[n * 5 + lane] : 0.f;
        float acc = bv;
        acc = fmaf(readlane_f(x, 0), w0, acc);
        acc = fmaf(readlane_f(x, 1), w1, acc);
        acc = fmaf(readlane_f(x, 2), w2, acc);
        acc = fmaf(readlane_f(x, 3), w3, acc);
        acc = fmaf(readlane_f(x, 4), w4, acc);
        Y[n * 64 + lane] = fmaxf(acc, 0.f);
    }
}

// MFMA node-gemm: Y[n,:] = act( [X1[n,:] (| X2[n,:])] @ W + b ), K = KT*32.
// 16 rows per wave-tile; B (weights) register-resident bf16; fp32 accumulate.
// OUT_BF16: store bf16 via lane-pair swap (dword stores).
template <int KT, int RELU, int OUT_BF16>
__global__ __launch_bounds__(256, 2)
void ngemm_kernel(const float* __restrict__ X1, const float* __restrict__ X2,
                  const float* __restrict__ W, const float* __restrict__ b,
                  void* __restrict__ Yv, int N) {
    int tid = threadIdx.x;
    int lane = tid & 63;
    int n15 = lane & 15, kg = lane >> 4;
    ABFrag bw[4][KT];
#pragma unroll
    for (int nt = 0; nt < 4; ++nt)
#pragma unroll
        for (int kt = 0; kt < KT; ++kt)
#pragma unroll
            for (int jj = 0; jj < 4; ++jj) {
                int k0 = kt * 32 + kg * 8 + 2 * jj;
                bw[nt][kt].i[jj] = pack2bf(W[(size_t)k0 * 64 + nt * 16 + n15],
                                           W[(size_t)(k0 + 1) * 64 + nt * 16 + n15]);
            }
    float bv[4];
#pragma unroll
    for (int nt = 0; nt < 4; ++nt) bv[nt] = b[nt * 16 + n15];

    int wid = (blockIdx.x * blockDim.x + tid) >> 6;
    int nw = (gridDim.x * blockDim.x) >> 6;
    int nTiles = (N + 15) >> 4;
    for (int t = wid; t < nTiles; t += nw) {
        int n0 = t << 4;
        int row = n0 + n15; if (row > N - 1) row = N - 1;
        const float* xp = X1 + (size_t)row * 64 + kg * 8;
        float4 xa = *(const float4*)xp;
        float4 xb = *(const float4*)(xp + 4);
        float4 xc = *(const float4*)(xp + 32);
        float4 xd = *(const float4*)(xp + 36);
        ABFrag A0, A1, A2, A3;
        A0.i[0] = pack2bf(xa.x, xa.y); A0.i[1] = pack2bf(xa.z, xa.w);
        A0.i[2] = pack2bf(xb.x, xb.y); A0.i[3] = pack2bf(xb.z, xb.w);
        A1.i[0] = pack2bf(xc.x, xc.y); A1.i[1] = pack2bf(xc.z, xc.w);
        A1.i[2] = pack2bf(xd.x, xd.y); A1.i[3] = pack2bf(xd.z, xd.w);
        if constexpr (KT == 4) {
            const float* yp = X2 + (size_t)row * 64 + kg * 8;
            float4 ya = *(const float4*)yp;
            float4 yb = *(const float4*)(yp + 4);
            float4 yc = *(const float4*)(yp + 32);
            float4 yd = *(const float4*)(yp + 36);
            A2.i[0] = pack2bf(ya.x, ya.y); A2.i[1] = pack2bf(ya.z, ya.w);
            A2.i[2] = pack2bf(yb.x, yb.y); A2.i[3] = pack2bf(yb.z, yb.w);
            A3.i[0] = pack2bf(yc.x, yc.y); A3.i[1] = pack2bf(yc.z, yc.w);
            A3.i[2] = pack2bf(yd.x, yd.y); A3.i[3] = pack2bf(yd.z, yd.w);
        }
        f32x4 acc[4];
#pragma unroll
        for (int nt = 0; nt < 4; ++nt) {
            acc[nt][0] = bv[nt]; acc[nt][1] = bv[nt];
            acc[nt][2] = bv[nt]; acc[nt][3] = bv[nt];
        }
#pragma unroll
        for (int nt = 0; nt < 4; ++nt) {
            acc[nt] = __builtin_amdgcn_mfma_f32_16x16x32_bf16(A0.v, bw[nt][0].v, acc[nt], 0, 0, 0);
            acc[nt] = __builtin_amdgcn_mfma_f32_16x16x32_bf16(A1.v, bw[nt][1].v, acc[nt], 0, 0, 0);
            if constexpr (KT == 4) {
                acc[nt] = __builtin_amdgcn_mfma_f32_16x16x32_bf16(A2.v, bw[nt][2].v, acc[nt], 0, 0, 0);
                acc[nt] = __builtin_amdgcn_mfma_f32_16x16x32_bf16(A3.v, bw[nt][3].v, acc[nt], 0, 0, 0);
            }
        }
        if constexpr (OUT_BF16) {
            unsigned short* Y = (unsigned short*)Yv;
            bool ev = ((n15 & 1) == 0);
#pragma unroll
            for (int nt = 0; nt < 4; ++nt) {
                float v0 = acc[nt][0], v1 = acc[nt][1], v2 = acc[nt][2], v3 = acc[nt][3];
                if (RELU) {
                    v0 = fmaxf(v0, 0.f); v1 = fmaxf(v1, 0.f);
                    v2 = fmaxf(v2, 0.f); v3 = fmaxf(v3, 0.f);
                }
                float o0 = __shfl_xor(v0, 1), o1 = __shfl_xor(v1, 1);
                float o2 = __shfl_xor(v2, 1), o3 = __shfl_xor(v3, 1);
                int colb = nt * 16 + (n15 & ~1);
                if (ev) {
                    int r0 = n0 + kg * 4 + 0, r1 = n0 + kg * 4 + 1;
                    if (r0 < N) *(int*)(Y + (size_t)r0 * 64 + colb) = pack2bf(v0, o0);
                    if (r1 < N) *(int*)(Y + (size_t)r1 * 64 + colb) = pack2bf(v1, o1);
                } else {
                    int r2 = n0 + kg * 4 + 2, r3 = n0 + kg * 4 + 3;
                    if (r2 < N) *(int*)(Y + (size_t)r2 * 64 + colb) = pack2bf(o2, v2);
                    if (r3 < N) *(int*)(Y + (size_t)r3 * 64 + colb) = pack2bf(o3, v3);
                }
            }
        } else {
            float* Y = (float*)Yv;
#pragma unroll
            for (int nt = 0; nt < 4; ++nt)
#pragma unroll
                for (int r = 0; r < 4; ++r) {
                    int rr = n0 + kg * 4 + r;
                    if (rr < N) {
                        float v = acc[nt][r];
                        if (RELU) v = fmaxf(v, 0.f);
                        Y[(size_t)rr * 64 + nt * 16 + n15] = v;
                    }
                }
        }
    }
}

// node-per-wave MFMA message kernel, NO atomics:
// wave owns dst node n; iterates its CSR edges in 16-row tiles;
// h[row] = relu(Gbf[src] + ce(f)) (ce from LDS piecewise-linear table, XOR-swizzled);
// m = relu(h @ W2 + b2) via 8x mfma; in-register row-reduction; mean; plain store.
__global__ __launch_bounds__(256, 2)
void msg_mfma_kernel(const unsigned short* __restrict__ Gbf, const int* __restrict__ rowstart,
                     const int* __restrict__ srcs, const float* __restrict__ feats,
                     const unsigned char* __restrict__ seg,
                     const float* __restrict__ Atab, const float* __restrict__ Btab,
                     const float* __restrict__ W2, const float* __restrict__ b2p,
                     float* __restrict__ Agg, int N) {
    __shared__ float sA[65 * 64], sB[65 * 64];
    int tid = threadIdx.x;
    for (int i = tid; i < 65 * 64; i += 256) {
        int sgi = i >> 6, c = i & 63;
        int pos = (sgi << 6) + ((((c >> 2) ^ (sgi & 7)) << 2) | (c & 3));
        sA[pos] = Atab[i];
        sB[pos] = Btab[i];
    }
    int lane = tid & 63;
    int n15 = lane & 15;
    int kg = lane >> 4;

    ABFrag bw[4][2];
#pragma unroll
    for (int nt = 0; nt < 4; ++nt)
#pragma unroll
        for (int kt = 0; kt < 2; ++kt)
#pragma unroll
            for (int jj = 0; jj < 4; ++jj) {
                int k0 = kt * 32 + kg * 8 + 2 * jj;
                bw[nt][kt].i[jj] = pack2bf(W2[(size_t)k0 * 64 + nt * 16 + n15],
                                           W2[(size_t)(k0 + 1) * 64 + nt * 16 + n15]);
            }
    float b2v[4];
#pragma unroll
    for (int nt = 0; nt < 4; ++nt) b2v[nt] = b2p[nt * 16 + n15];
    __syncthreads();

    int wid = (blockIdx.x * blockDim.x + tid) >> 6;
    int nw = (gridDim.x * blockDim.x) >> 6;
    for (int n = wid; n < N; n += nw) {
        int beg = rowstart[n], end = rowstart[n + 1];
        int d = end - beg;
        float na0 = 0.f, na1 = 0.f, na2 = 0.f, na3 = 0.f;
        for (int t0 = beg; t0 < end; t0 += 16) {
            int e = t0 + n15;
            int ec = (e < end) ? e : beg;
            float f = feats[ec];
            int src = srcs[ec];
            int sg = (int)seg[ec];
            int sgb = sg << 6;
            int sx = sg & 7;
            const unsigned short* gp = Gbf + (size_t)src * 64 + kg * 8;
            int4 ga = *(const int4*)gp;
            int4 gb = *(const int4*)(gp + 32);
            int q0 = (kg * 2) ^ sx;
            int q1 = (kg * 2 + 1) ^ sx;
            int q2 = (kg * 2 + 8) ^ sx;
            int q3 = (kg * 2 + 9) ^ sx;
            float4 ta0 = *(const float4*)&sA[sgb + (q0 << 2)];
            float4 tb0 = *(const float4*)&sB[sgb + (q0 << 2)];
            float4 ta1 = *(const float4*)&sA[sgb + (q1 << 2)];
            float4 tb1 = *(const float4*)&sB[sgb + (q1 << 2)];
            float4 ta2 = *(const float4*)&sA[sgb + (q2 << 2)];
            float4 tb2 = *(const float4*)&sB[sgb + (q2 << 2)];
            float4 ta3 = *(const float4*)&sA[sgb + (q3 << 2)];
            float4 tb3 = *(const float4*)&sB[sgb + (q3 << 2)];
            float h0 = fmaxf(bflo(ga.x) + fmaf(f, tb0.x, ta0.x), 0.f);
            float h1 = fmaxf(bfhi(ga.x) + fmaf(f, tb0.y, ta0.y), 0.f);
            float h2 = fmaxf(bflo(ga.y) + fmaf(f, tb0.z, ta0.z), 0.f);
            float h3 = fmaxf(bfhi(ga.y) + fmaf(f, tb0.w, ta0.w), 0.f);
            float h4 = fmaxf(bflo(ga.z) + fmaf(f, tb1.x, ta1.x), 0.f);
            float h5 = fmaxf(bfhi(ga.z) + fmaf(f, tb1.y, ta1.y), 0.f);
            float h6 = fmaxf(bflo(ga.w) + fmaf(f, tb1.z, ta1.z), 0.f);
            float h7 = fmaxf(bfhi(ga.w) + fmaf(f, tb1.w, ta1.w), 0.f);
            float h8 = fmaxf(bflo(gb.x) + fmaf(f, tb2.x, ta2.x), 0.f);
            float h9 = fmaxf(bfhi(gb.x) + fmaf(f, tb2.y, ta2.y), 0.f);
            float h10 = fmaxf(bflo(gb.y) + fmaf(f, tb2.z, ta2.z), 0.f);
            float h11 = fmaxf(bfhi(gb.y) + fmaf(f, tb2.w, ta2.w), 0.f);
            float h12 = fmaxf(bflo(gb.z) + fmaf(f, tb3.x, ta3.x), 0.f);
            float h13 = fmaxf(bfhi(gb.z) + fmaf(f, tb3.y, ta3.y), 0.f);
            float h14 = fmaxf(bflo(gb.w) + fmaf(f, tb3.z, ta3.z), 0.f);
            float h15 = fmaxf(bfhi(gb.w) + fmaf(f, tb3.w, ta3.w), 0.f);
            ABFrag A0, A1;
            A0.i[0] = pack2bf(h0, h1);
            A0.i[1] = pack2bf(h2, h3);
            A0.i[2] = pack2bf(h4, h5);
            A0.i[3] = pack2bf(h6, h7);
            A1.i[0] = pack2bf(h8, h9);
            A1.i[1] = pack2bf(h10, h11);
            A1.i[2] = pack2bf(h12, h13);
            A1.i[3] = pack2bf(h14, h15);
            f32x4 acc[4];
#pragma unroll
            for (int nt = 0; nt < 4; ++nt) {
                acc[nt][0] = b2v[nt]; acc[nt][1] = b2v[nt];
                acc[nt][2] = b2v[nt]; acc[nt][3] = b2v[nt];
            }
#pragma unroll
            for (int nt = 0; nt < 4; ++nt) {
                acc[nt] = __builtin_amdgcn_mfma_f32_16x16x32_bf16(A0.v, bw[nt][0].v, acc[nt], 0, 0, 0);
                acc[nt] = __builtin_amdgcn_mfma_f32_16x16x32_bf16(A1.v, bw[nt][1].v, acc[nt], 0, 0, 0);
            }
            // mask padded rows (row = kg*4+r valid iff < rem), relu, reduce 16 rows
            int rem = end - t0;
            float rs0, rs1, rs2, rs3;
            {
                float m0 = (kg * 4 + 0 < rem) ? fmaxf(acc[0][0], 0.f) : 0.f;
                float m1 = (kg * 4 + 1 < rem) ? fmaxf(acc[0][1], 0.f) : 0.f;
                float m2 = (kg * 4 + 2 < rem) ? fmaxf(acc[0][2], 0.f) : 0.f;
                float m3 = (kg * 4 + 3 < rem) ? fmaxf(acc[0][3], 0.f) : 0.f;
                rs0 = (m0 + m1) + (m2 + m3);
            }
            {
                float m0 = (kg * 4 + 0 < rem) ? fmaxf(acc[1][0], 0.f) : 0.f;
                float m1 = (kg * 4 + 1 < rem) ? fmaxf(acc[1][1], 0.f) : 0.f;
                float m2 = (kg * 4 + 2 < rem) ? fmaxf(acc[1][2], 0.f) : 0.f;
                float m3 = (kg * 4 + 3 < rem) ? fmaxf(acc[1][3], 0.f) : 0.f;
                rs1 = (m0 + m1) + (m2 + m3);
            }
            {
                float m0 = (kg * 4 + 0 < rem) ? fmaxf(acc[2][0], 0.f) : 0.f;
                float m1 = (kg * 4 + 1 < rem) ? fmaxf(acc[2][1], 0.f) : 0.f;
                float m2 = (kg * 4 + 2 < rem) ? fmaxf(acc[2][2], 0.f) : 0.f;
                float m3 = (kg * 4 + 3 < rem) ? fmaxf(acc[2][3], 0.f) : 0.f;
                rs2 = (m0 + m1) + (m2 + m3);
            }
            {
                float m0 = (kg * 4 + 0 < rem) ? fmaxf(acc[3][0], 0.f) : 0.f;
                float m1 = (kg * 4 + 1 < rem) ? fmaxf(acc[3][1], 0.f) : 0.f;
                float m2 = (kg * 4 + 2 < rem) ? fmaxf(acc[3][2], 0.f) : 0.f;
                float m3 = (kg * 4 + 3 < rem) ? fmaxf(acc[3][3], 0.f) : 0.f;
                rs3 = (m0 + m1) + (m2 + m3);
            }
            rs0 += __shfl_xor(rs0, 16); rs0 += __shfl_xor(rs0, 32);
            rs1 += __shfl_xor(rs1, 16); rs1 += __shfl_xor(rs1, 32);
            rs2 += __shfl_xor(rs2, 16); rs2 += __shfl_xor(rs2, 32);
            rs3 += __shfl_xor(rs3, 16); rs3 += __shfl_xor(rs3, 32);
            na0 += rs0; na1 += rs1; na2 += rs2; na3 += rs3;
        }
        float invd = (d > 0) ? (1.f / (float)d) : 1.f;
        if (kg == 0) {
            Agg[(size_t)n * 64 + 0 * 16 + n15] = na0 * invd;
            Agg[(size_t)n * 64 + 1 * 16 + n15] = na1 * invd;
            Agg[(size_t)n * 64 + 2 * 16 + n15] = na2 * invd;
            Agg[(size_t)n * 64 + 3 * 16 + n15] = na3 * invd;
        }
    }
}

// head tail: T already = relu(h@oW1+ob1); pred[c] = sum_j T[j]*W2[j,c]+b2[c]; 2pi*sigmoid
__global__ __launch_bounds__(256, 2)
void head2_kernel(const float* __restrict__ T, const float* __restrict__ W2,
                  const float* __restrict__ b2, float* __restrict__ out, int N) {
    int lane = threadIdx.x & 63;
    float w2c0 = W2[lane * 3 + 0], w2c1 = W2[lane * 3 + 1], w2c2 = W2[lane * 3 + 2];
    float b20 = b2[0], b21 = b2[1], b22 = b2[2];
    int wid = (blockIdx.x * blockDim.x + threadIdx.x) >> 6;
    int nw = (gridDim.x * blockDim.x) >> 6;
    const float TWO_PI = 6.283185307179586f;
    for (int n = wid; n < N; n += nw) {
        float t = T[(size_t)n * 64 + lane];
        float p0 = t * w2c0, p1 = t * w2c1, p2 = t * w2c2;
#pragma unroll
        for (int off = 32; off > 0; off >>= 1) {
            p0 += __shfl_xor(p0, off);
            p1 += __shfl_xor(p1, off);
            p2 += __shfl_xor(p2, off);
        }
        if (lane == 0) {
            float v0 = p0 + b20, v1 = p1 + b21, v2 = p2 + b22;
            out[n * 3 + 0] = TWO_PI / (1.f + expf(-v0));
            out[n * 3 + 1] = TWO_PI / (1.f + expf(-v1));
            out[n * 3 + 2] = TWO_PI / (1.f + expf(-v2));
        }
    }
}

extern "C" void kernel_launch(void* const* d_in, const int* in_sizes, int n_in,
                              void* d_out, int out_size, void* d_ws, size_t ws_size,
                              hipStream_t stream) {
    const float* nf    = (const float*)d_in[0];
    const int*   ei    = (const int*)d_in[1];
    const float* ef    = (const float*)d_in[2];
    const float* encW1 = (const float*)d_in[3];
    const float* encb1 = (const float*)d_in[4];
    const float* encW2 = (const float*)d_in[5];
    const float* encb2 = (const float*)d_in[6];
    const float* eeW   = (const float*)d_in[7];
    const float* eeb   = (const float*)d_in[8];
    const float* mW1   = (const float*)d_in[9];
    const float* mb1   = (const float*)d_in[10];
    const float* mW2   = (const float*)d_in[11];
    const float* mb2   = (const float*)d_in[12];
    const float* uW1   = (const float*)d_in[13];
    const float* ub1   = (const float*)d_in[14];
    const float* uW2   = (const float*)d_in[15];
    const float* ub2   = (const float*)d_in[16];
    const float* oW1   = (const float*)d_in[17];
    const float* ob1   = (const float*)d_in[18];
    const float* oW2   = (const float*)d_in[19];
    const float* ob2   = (const float*)d_in[20];
    float* out = (float*)d_out;

    int N = in_sizes[0] / 5;   // 50000
    int E = in_sizes[2];       // 800000
    size_t N64 = (size_t)N * 64;

    float* ws = (float*)d_ws;
    float* f0 = ws;                 // h / hn (alternating)
    float* f1 = f0 + N64;           // agg / hn (alternating)
    float* f2 = f1 + N64;           // t / enc tmp
    unsigned short* gbf = (unsigned short*)(f2 + N64);   // N64 bf16
    float* feats = f2 + N64 + N64 / 2;                   // E
    float* bp    = feats + E;                            // 64
    float* Atab  = bp + 64;                              // 3*65*64
    float* Btab  = Atab + 3 * 65 * 64;                   // 3*65*64
    int* rowstart = (int*)(Btab + 3 * 65 * 64);          // N+8
    int* cursor   = rowstart + N + 8;                    // N
    int* dcnt     = cursor + N;                          // N
    int* srcs     = dcnt + N;                            // E
    unsigned char* seg = (unsigned char*)(srcs + E);     // E

    int gemmBlocks = ((N + 15) / 16 + 3) / 4;            // 1 tile per wave

    // piecewise-linear tables for the edge-encoder->W1b path
    bp_kernel<<<1, 64, 0, stream>>>(eeW, eeb, bp);
    tab_kernel<<<195, 64, 0, stream>>>(eeW, eeb, mW1, bp, Atab, Btab);

    // node encoder
    enc1_kernel<<<512, 256, 0, stream>>>(nf, encW1, encb1, f2, N);
    ngemm_kernel<2, 1, 0><<<gemmBlocks, 256, 0, stream>>>(f2, nullptr, encW2, encb2, f0, N);

    // CSR build (dst-sorted edge list) + per-edge table segment
    zero_int_kernel<<<256, 256, 0, stream>>>(dcnt, N);
    hist_kernel<<<(E + 255) / 256, 256, 0, stream>>>(ei, dcnt, E);
    scan_kernel<<<1, 1024, 0, stream>>>(dcnt, rowstart, cursor, N);
    fill_kernel<<<(E + 255) / 256, 256, 0, stream>>>(ei, ef, bp, cursor, srcs, feats, seg, E);

    float* h = f0;
    float* o = f1;   // agg, then reused for hn
    for (int l = 0; l < 3; ++l) {
        const float* W1a = mW1 + (size_t)l * 128 * 64;
        const float* b1  = mb1 + l * 64;
        const float* W2  = mW2 + (size_t)l * 64 * 64;
        const float* b2  = mb2 + l * 64;
        // gbf = bf16(h @ W1a + b1)   (src-side half of message concat-matmul)
        ngemm_kernel<2, 0, 1><<<gemmBlocks, 256, 0, stream>>>(h, nullptr, W1a, b1, gbf, N);
        // agg(=o) = mean of relu(relu(G+ce)@W2+b2) over in-edges, no atomics
        msg_mfma_kernel<<<1024, 256, 0, stream>>>(gbf, rowstart, srcs, feats, seg,
                                                  Atab + (size_t)l * 65 * 64,
                                                  Btab + (size_t)l * 65 * 64,
                                                  W2, b2, o, N);
        const float* U1 = uW1 + (size_t)l * 128 * 64;
        const float* v1 = ub1 + l * 64;
        const float* U2 = uW2 + (size_t)l * 64 * 64;
        const float* v2 = ub2 + l * 64;
        // t = relu([h | agg] @ U1 + v1)  (fused K=128)
        ngemm_kernel<4, 1, 0><<<gemmBlocks, 256, 0, stream>>>(h, o, U1, v1, f2, N);
        // hn = relu(t @ U2 + v2) -> into o (agg consumed)
        ngemm_kernel<2, 1, 0><<<gemmBlocks, 256, 0, stream>>>(f2, nullptr, U2, v2, o, N);
        float* tmp = h; h = o; o = tmp;
    }

    // head
    ngemm_kernel<2, 1, 0><<<gemmBlocks, 256, 0, stream>>>(h, nullptr, oW1, ob1, f2, N);
    head2_kernel<<<1024, 256, 0, stream>>>(f2, oW2, ob2, out, N);
}

// Round 7
// 356.376 us; speedup vs baseline: 11.2533x; 1.3412x over previous
//
#include <hip/hip_runtime.h>
#include <math.h>

typedef short bf16x8 __attribute__((ext_vector_type(8)));
typedef float f32x4 __attribute__((ext_vector_type(4)));

union ABFrag { int i[4]; bf16x8 v; };

__device__ __forceinline__ float readlane_f(float v, int l) {
    return __uint_as_float(__builtin_amdgcn_readlane(__float_as_uint(v), l));
}

// pack two f32 -> two bf16 (RNE) in one u32 (lo = a, hi = b)
__device__ __forceinline__ int pack2bf(float a, float b) {
    unsigned ua = __float_as_uint(a);
    unsigned ub = __float_as_uint(b);
    ua = (ua + 0x7FFFu + ((ua >> 16) & 1u)) >> 16;
    ub = (ub + 0x7FFFu + ((ub >> 16) & 1u)) & 0xFFFF0000u;
    return (int)(ua | ub);
}
__device__ __forceinline__ float bflo(int d) { return __uint_as_float((unsigned)d << 16); }
__device__ __forceinline__ float bfhi(int d) { return __uint_as_float((unsigned)d & 0xFFFF0000u); }

__global__ void zero_int_kernel(int* __restrict__ p, int n) {
    int i = blockIdx.x * blockDim.x + threadIdx.x;
    int stride = gridDim.x * blockDim.x;
    for (; i < n; i += stride) p[i] = 0;
}

__global__ void hist_kernel(const int* __restrict__ EI, int* __restrict__ cnt, int E) {
    int e = blockIdx.x * blockDim.x + threadIdx.x;
    if (e < E) atomicAdd(&cnt[EI[E + e]], 1);
}

// ---- multi-block exclusive scan: cnt[N] -> rowstart[N+1], cursor[N] ----
#define SCAN_B 256

__global__ __launch_bounds__(256)
void scan_part_kernel(const int* __restrict__ cnt, int* __restrict__ bsum, int N) {
    int per = (N + gridDim.x - 1) / gridDim.x;
    int lo = blockIdx.x * per;
    int hi = lo + per; if (hi > N) hi = N;
    int s = 0;
    for (int i = lo + threadIdx.x; i < hi; i += 256) s += cnt[i];
#pragma unroll
    for (int off = 32; off >= 1; off >>= 1) s += __shfl_xor(s, off);
    __shared__ int ws[4];
    if ((threadIdx.x & 63) == 0) ws[threadIdx.x >> 6] = s;
    __syncthreads();
    if (threadIdx.x == 0) bsum[blockIdx.x] = ws[0] + ws[1] + ws[2] + ws[3];
}

__global__ __launch_bounds__(SCAN_B)
void scan_mid_kernel(int* __restrict__ bsum) {
    __shared__ int sbuf[SCAN_B];
    int tid = threadIdx.x;
    int v = bsum[tid];
    sbuf[tid] = v;
    __syncthreads();
#pragma unroll
    for (int d = 1; d < SCAN_B; d <<= 1) {
        int t = (tid >= d) ? sbuf[tid - d] : 0;
        __syncthreads();
        sbuf[tid] += t;
        __syncthreads();
    }
    bsum[tid] = sbuf[tid] - v;   // exclusive
}

__global__ __launch_bounds__(256)
void scan_final_kernel(const int* __restrict__ cnt, const int* __restrict__ bsum,
                       int* __restrict__ rowstart, int* __restrict__ cursor, int N) {
    __shared__ int sbuf[256];
    __shared__ int sbase;
    int per = (N + gridDim.x - 1) / gridDim.x;
    int lo = blockIdx.x * per;
    int hi = lo + per; if (hi > N) hi = N;
    if (threadIdx.x == 0) sbase = bsum[blockIdx.x];
    __syncthreads();
    for (int base = lo; base < hi; base += 256) {
        int i = base + threadIdx.x;
        int v = (i < hi) ? cnt[i] : 0;
        sbuf[threadIdx.x] = v;
        __syncthreads();
#pragma unroll
        for (int d = 1; d < 256; d <<= 1) {
            int t = (threadIdx.x >= d) ? sbuf[threadIdx.x - d] : 0;
            __syncthreads();
            sbuf[threadIdx.x] += t;
            __syncthreads();
        }
        if (i < hi) {
            int ex = sbase + sbuf[threadIdx.x] - v;
            rowstart[i] = ex;
            cursor[i] = ex;
        }
        __syncthreads();
        if (threadIdx.x == 0) sbase += sbuf[255];
        __syncthreads();
    }
    if (blockIdx.x == gridDim.x - 1 && threadIdx.x == 0) rowstart[N] = sbase;
}

// scatter edges into dst-sorted slots; pack (src | seg<<25, f) into int2
__global__ __launch_bounds__(256)
void fill_kernel(const int* __restrict__ EI, const float* __restrict__ EF,
                 const float* __restrict__ bp, int* __restrict__ cursor,
                 int2* __restrict__ epack, int E) {
    __shared__ float sbp[64];
    if (threadIdx.x < 64) sbp[threadIdx.x] = bp[threadIdx.x];
    __syncthreads();
    int e = blockIdx.x * blockDim.x + threadIdx.x;
    if (e < E) {
        int dst = EI[E + e];
        int slot = atomicAdd(&cursor[dst], 1);
        float f = EF[e];
        int sg = 0;
#pragma unroll
        for (int st = 32; st >= 1; st >>= 1)
            if (sg + st <= 64 && sbp[sg + st - 1] < f) sg += st;
        epack[slot] = make_int2(EI[e] | (sg << 25), __float_as_int(f));
    }
}

// sorted breakpoints of f -> relu(f*eW+eB): t_k = -eB_k/eW_k (eW_k != 0)
__global__ __launch_bounds__(64)
void bp_kernel(const float* __restrict__ eW, const float* __restrict__ eB,
               float* __restrict__ bp) {
    int lane = threadIdx.x;
    float w = eW[lane], b = eB[lane];
    float t = (w != 0.f) ? (-b / w) : 1e30f;
    __shared__ float sbp[64];
    int rank = 0;
    for (int j = 0; j < 64; ++j) {
        float tj = readlane_f(t, j);
        rank += (tj < t) || (tj == t && j < lane);
    }
    sbp[rank] = t;
    __syncthreads();
    bp[lane] = sbp[lane];
}

// per (layer, segment): A[j] = sum_{k active} eB_k*W1b[k][j], B[j] = sum eW_k*W1b[k][j]
__global__ __launch_bounds__(64)
void tab_kernel(const float* __restrict__ eW, const float* __restrict__ eB,
                const float* __restrict__ mW1, const float* __restrict__ bp,
                float* __restrict__ Atab, float* __restrict__ Btab) {
    int s = blockIdx.x % 65;
    int l = blockIdx.x / 65;
    int j = threadIdx.x;
    float lo = (s == 0) ? 0.f : bp[s - 1];
    float hi = (s == 64) ? 0.f : bp[s];
    float rep;
    if (s == 0) rep = hi - fmaxf(1.f, fabsf(hi));
    else if (s == 64) rep = lo + fmaxf(1.f, fabsf(lo));
    else rep = 0.5f * (lo + hi);
    const float* W1b = mW1 + (size_t)l * 128 * 64 + 64 * 64;
    float A = 0.f, B = 0.f;
    for (int k = 0; k < 64; ++k) {
        float w = eW[k], b = eB[k];
        if (fmaf(rep, w, b) > 0.f) {
            float wv = W1b[k * 64 + j];
            A = fmaf(b, wv, A);
            B = fmaf(w, wv, B);
        }
    }
    Atab[((size_t)l * 65 + s) * 64 + j] = A;
    Btab[((size_t)l * 65 + s) * 64 + j] = B;
}

// first encoder layer: Y[n,j] = relu(b[j] + sum_{k<5} NF[n,k]*W[k,j])
__global__ __launch_bounds__(256)
void enc1_kernel(const float* __restrict__ NF, const float* __restrict__ W,
                 const float* __restrict__ b, float* __restrict__ Y, int N) {
    int lane = threadIdx.x & 63;
    float w0 = W[0 * 64 + lane], w1 = W[1 * 64 + lane], w2 = W[2 * 64 + lane];
    float w3 = W[3 * 64 + lane], w4 = W[4 * 64 + lane];
    float bv = b[lane];
    int wid = (blockIdx.x * blockDim.x + threadIdx.x) >> 6;
    int nw = (gridDim.x * blockDim.x) >> 6;
    for (int n = wid; n < N; n += nw) {
        float x = (lane < 5) ? NF[n * 5 + lane] : 0.f;
        float acc = bv;
        acc = fmaf(readlane_f(x, 0), w0, acc);
        acc = fmaf(readlane_f(x, 1), w1, acc);
        acc = fmaf(readlane_f(x, 2), w2, acc);
        acc = fmaf(readlane_f(x, 3), w3, acc);
        acc = fmaf(readlane_f(x, 4), w4, acc);
        Y[n * 64 + lane] = fmaxf(acc, 0.f);
    }
}

// MFMA node-gemm: Y[n,:] = act( X1[n,:] @ W + b ), K=64, 16 rows/wave-tile.
template <int RELU, int OUT_BF16>
__global__ __launch_bounds__(256, 2)
void ngemm_kernel(const float* __restrict__ X1, const float* __restrict__ W,
                  const float* __restrict__ b, void* __restrict__ Yv, int N) {
    int tid = threadIdx.x;
    int lane = tid & 63;
    int n15 = lane & 15, kg = lane >> 4;
    ABFrag bw[4][2];
#pragma unroll
    for (int nt = 0; nt < 4; ++nt)
#pragma unroll
        for (int kt = 0; kt < 2; ++kt)
#pragma unroll
            for (int jj = 0; jj < 4; ++jj) {
                int k0 = kt * 32 + kg * 8 + 2 * jj;
                bw[nt][kt].i[jj] = pack2bf(W[(size_t)k0 * 64 + nt * 16 + n15],
                                           W[(size_t)(k0 + 1) * 64 + nt * 16 + n15]);
            }
    float bv[4];
#pragma unroll
    for (int nt = 0; nt < 4; ++nt) bv[nt] = b[nt * 16 + n15];

    int wid = (blockIdx.x * blockDim.x + tid) >> 6;
    int nw = (gridDim.x * blockDim.x) >> 6;
    int nTiles = (N + 15) >> 4;
    for (int t = wid; t < nTiles; t += nw) {
        int n0 = t << 4;
        int row = n0 + n15; if (row > N - 1) row = N - 1;
        const float* xp = X1 + (size_t)row * 64 + kg * 8;
        float4 xa = *(const float4*)xp;
        float4 xb = *(const float4*)(xp + 4);
        float4 xc = *(const float4*)(xp + 32);
        float4 xd = *(const float4*)(xp + 36);
        ABFrag A0, A1;
        A0.i[0] = pack2bf(xa.x, xa.y); A0.i[1] = pack2bf(xa.z, xa.w);
        A0.i[2] = pack2bf(xb.x, xb.y); A0.i[3] = pack2bf(xb.z, xb.w);
        A1.i[0] = pack2bf(xc.x, xc.y); A1.i[1] = pack2bf(xc.z, xc.w);
        A1.i[2] = pack2bf(xd.x, xd.y); A1.i[3] = pack2bf(xd.z, xd.w);
        f32x4 acc[4];
#pragma unroll
        for (int nt = 0; nt < 4; ++nt) {
            acc[nt][0] = bv[nt]; acc[nt][1] = bv[nt];
            acc[nt][2] = bv[nt]; acc[nt][3] = bv[nt];
        }
#pragma unroll
        for (int nt = 0; nt < 4; ++nt) {
            acc[nt] = __builtin_amdgcn_mfma_f32_16x16x32_bf16(A0.v, bw[nt][0].v, acc[nt], 0, 0, 0);
            acc[nt] = __builtin_amdgcn_mfma_f32_16x16x32_bf16(A1.v, bw[nt][1].v, acc[nt], 0, 0, 0);
        }
        if constexpr (OUT_BF16) {
            unsigned short* Y = (unsigned short*)Yv;
            bool ev = ((n15 & 1) == 0);
#pragma unroll
            for (int nt = 0; nt < 4; ++nt) {
                float v0 = acc[nt][0], v1 = acc[nt][1], v2 = acc[nt][2], v3 = acc[nt][3];
                if (RELU) {
                    v0 = fmaxf(v0, 0.f); v1 = fmaxf(v1, 0.f);
                    v2 = fmaxf(v2, 0.f); v3 = fmaxf(v3, 0.f);
                }
                float o0 = __shfl_xor(v0, 1), o1 = __shfl_xor(v1, 1);
                float o2 = __shfl_xor(v2, 1), o3 = __shfl_xor(v3, 1);
                int colb = nt * 16 + (n15 & ~1);
                if (ev) {
                    int r0 = n0 + kg * 4 + 0, r1 = n0 + kg * 4 + 1;
                    if (r0 < N) *(int*)(Y + (size_t)r0 * 64 + colb) = pack2bf(v0, o0);
                    if (r1 < N) *(int*)(Y + (size_t)r1 * 64 + colb) = pack2bf(v1, o1);
                } else {
                    int r2 = n0 + kg * 4 + 2, r3 = n0 + kg * 4 + 3;
                    if (r2 < N) *(int*)(Y + (size_t)r2 * 64 + colb) = pack2bf(o2, v2);
                    if (r3 < N) *(int*)(Y + (size_t)r3 * 64 + colb) = pack2bf(o3, v3);
                }
            }
        } else {
            float* Y = (float*)Yv;
#pragma unroll
            for (int nt = 0; nt < 4; ++nt)
#pragma unroll
                for (int r = 0; r < 4; ++r) {
                    int rr = n0 + kg * 4 + r;
                    if (rr < N) {
                        float v = acc[nt][r];
                        if (RELU) v = fmaxf(v, 0.f);
                        Y[(size_t)rr * 64 + nt * 16 + n15] = v;
                    }
                }
        }
    }
}

// fused update MLP: Y = relu( relu([X1|X2]@U1 + v1) @ U2 + v2 )
// intermediate t re-enters MFMA A-layout via per-wave bf16 LDS tile (stride 72)
__global__ __launch_bounds__(256, 2)
void upd_kernel(const float* __restrict__ X1, const float* __restrict__ X2,
                const float* __restrict__ U1, const float* __restrict__ v1,
                const float* __restrict__ U2, const float* __restrict__ v2,
                float* __restrict__ Y, int N) {
    __shared__ unsigned short sT[4][16 * 72];
    int tid = threadIdx.x, lane = tid & 63, w = tid >> 6;
    int n15 = lane & 15, kg = lane >> 4;
    unsigned short* T = sT[w];

    ABFrag bw1[4][4], bw2[4][2];
#pragma unroll
    for (int nt = 0; nt < 4; ++nt) {
#pragma unroll
        for (int kt = 0; kt < 4; ++kt)
#pragma unroll
            for (int jj = 0; jj < 4; ++jj) {
                int k0 = kt * 32 + kg * 8 + 2 * jj;
                bw1[nt][kt].i[jj] = pack2bf(U1[(size_t)k0 * 64 + nt * 16 + n15],
                                            U1[(size_t)(k0 + 1) * 64 + nt * 16 + n15]);
            }
#pragma unroll
        for (int kt = 0; kt < 2; ++kt)
#pragma unroll
            for (int jj = 0; jj < 4; ++jj) {
                int k0 = kt * 32 + kg * 8 + 2 * jj;
                bw2[nt][kt].i[jj] = pack2bf(U2[(size_t)k0 * 64 + nt * 16 + n15],
                                            U2[(size_t)(k0 + 1) * 64 + nt * 16 + n15]);
            }
    }
    float b1v[4], b2v[4];
#pragma unroll
    for (int nt = 0; nt < 4; ++nt) { b1v[nt] = v1[nt * 16 + n15]; b2v[nt] = v2[nt * 16 + n15]; }

    int wid = (blockIdx.x * blockDim.x + tid) >> 6;
    int nw = (gridDim.x * blockDim.x) >> 6;
    int nTiles = (N + 15) >> 4;
    for (int t = wid; t < nTiles; t += nw) {
        int n0 = t << 4;
        int row = n0 + n15; if (row > N - 1) row = N - 1;
        const float* xp = X1 + (size_t)row * 64 + kg * 8;
        float4 xa = *(const float4*)xp;
        float4 xb = *(const float4*)(xp + 4);
        float4 xc = *(const float4*)(xp + 32);
        float4 xd = *(const float4*)(xp + 36);
        const float* yp = X2 + (size_t)row * 64 + kg * 8;
        float4 ya = *(const float4*)yp;
        float4 yb = *(const float4*)(yp + 4);
        float4 yc = *(const float4*)(yp + 32);
        float4 yd = *(const float4*)(yp + 36);
        ABFrag A0, A1, A2, A3;
        A0.i[0] = pack2bf(xa.x, xa.y); A0.i[1] = pack2bf(xa.z, xa.w);
        A0.i[2] = pack2bf(xb.x, xb.y); A0.i[3] = pack2bf(xb.z, xb.w);
        A1.i[0] = pack2bf(xc.x, xc.y); A1.i[1] = pack2bf(xc.z, xc.w);
        A1.i[2] = pack2bf(xd.x, xd.y); A1.i[3] = pack2bf(xd.z, xd.w);
        A2.i[0] = pack2bf(ya.x, ya.y); A2.i[1] = pack2bf(ya.z, ya.w);
        A2.i[2] = pack2bf(yb.x, yb.y); A2.i[3] = pack2bf(yb.z, yb.w);
        A3.i[0] = pack2bf(yc.x, yc.y); A3.i[1] = pack2bf(yc.z, yc.w);
        A3.i[2] = pack2bf(yd.x, yd.y); A3.i[3] = pack2bf(yd.z, yd.w);
        f32x4 a1[4];
#pragma unroll
        for (int nt = 0; nt < 4; ++nt) {
            a1[nt][0] = b1v[nt]; a1[nt][1] = b1v[nt];
            a1[nt][2] = b1v[nt]; a1[nt][3] = b1v[nt];
        }
#pragma unroll
        for (int nt = 0; nt < 4; ++nt) {
            a1[nt] = __builtin_amdgcn_mfma_f32_16x16x32_bf16(A0.v, bw1[nt][0].v, a1[nt], 0, 0, 0);
            a1[nt] = __builtin_amdgcn_mfma_f32_16x16x32_bf16(A1.v, bw1[nt][1].v, a1[nt], 0, 0, 0);
            a1[nt] = __builtin_amdgcn_mfma_f32_16x16x32_bf16(A2.v, bw1[nt][2].v, a1[nt], 0, 0, 0);
            a1[nt] = __builtin_amdgcn_mfma_f32_16x16x32_bf16(A3.v, bw1[nt][3].v, a1[nt], 0, 0, 0);
        }
        // t (relu, bf16) -> per-wave LDS tile, stride 72
        asm volatile("s_waitcnt lgkmcnt(0)" ::: "memory");
        __builtin_amdgcn_sched_barrier(0);
        bool ev = ((n15 & 1) == 0);
#pragma unroll
        for (int nt = 0; nt < 4; ++nt) {
            float v0 = fmaxf(a1[nt][0], 0.f), v1 = fmaxf(a1[nt][1], 0.f);
            float v2 = fmaxf(a1[nt][2], 0.f), v3 = fmaxf(a1[nt][3], 0.f);
            float o0 = __shfl_xor(v0, 1), o1 = __shfl_xor(v1, 1);
            float o2 = __shfl_xor(v2, 1), o3 = __shfl_xor(v3, 1);
            int colb = nt * 16 + (n15 & ~1);
            if (ev) {
                *(int*)(T + (kg * 4 + 0) * 72 + colb) = pack2bf(v0, o0);
                *(int*)(T + (kg * 4 + 1) * 72 + colb) = pack2bf(v1, o1);
            } else {
                *(int*)(T + (kg * 4 + 2) * 72 + colb) = pack2bf(o2, v2);
                *(int*)(T + (kg * 4 + 3) * 72 + colb) = pack2bf(o3, v3);
            }
        }
        asm volatile("s_waitcnt lgkmcnt(0)" ::: "memory");
        __builtin_amdgcn_sched_barrier(0);
        ABFrag T0, T1;
        *(int4*)T0.i = *(const int4*)(T + n15 * 72 + kg * 8);
        *(int4*)T1.i = *(const int4*)(T + n15 * 72 + 32 + kg * 8);
        f32x4 a2[4];
#pragma unroll
        for (int nt = 0; nt < 4; ++nt) {
            a2[nt][0] = b2v[nt]; a2[nt][1] = b2v[nt];
            a2[nt][2] = b2v[nt]; a2[nt][3] = b2v[nt];
        }
#pragma unroll
        for (int nt = 0; nt < 4; ++nt) {
            a2[nt] = __builtin_amdgcn_mfma_f32_16x16x32_bf16(T0.v, bw2[nt][0].v, a2[nt], 0, 0, 0);
            a2[nt] = __builtin_amdgcn_mfma_f32_16x16x32_bf16(T1.v, bw2[nt][1].v, a2[nt], 0, 0, 0);
        }
#pragma unroll
        for (int nt = 0; nt < 4; ++nt)
#pragma unroll
            for (int r = 0; r < 4; ++r) {
                int rr = n0 + kg * 4 + r;
                if (rr < N) Y[(size_t)rr * 64 + nt * 16 + n15] = fmaxf(a2[nt][r], 0.f);
            }
    }
}

// node-per-wave MFMA message kernel (no atomics), epack = (src|seg<<25, f)
__global__ __launch_bounds__(256, 2)
void msg_mfma_kernel(const unsigned short* __restrict__ Gbf, const int* __restrict__ rowstart,
                     const int2* __restrict__ epack,
                     const float* __restrict__ Atab, const float* __restrict__ Btab,
                     const float* __restrict__ W2, const float* __restrict__ b2p,
                     float* __restrict__ Agg, int N) {
    __shared__ float sA[65 * 64], sB[65 * 64];
    int tid = threadIdx.x;
    for (int i = tid; i < 65 * 64; i += 256) {
        int sgi = i >> 6, c = i & 63;
        int pos = (sgi << 6) + ((((c >> 2) ^ (sgi & 7)) << 2) | (c & 3));
        sA[pos] = Atab[i];
        sB[pos] = Btab[i];
    }
    int lane = tid & 63;
    int n15 = lane & 15;
    int kg = lane >> 4;

    ABFrag bw[4][2];
#pragma unroll
    for (int nt = 0; nt < 4; ++nt)
#pragma unroll
        for (int kt = 0; kt < 2; ++kt)
#pragma unroll
            for (int jj = 0; jj < 4; ++jj) {
                int k0 = kt * 32 + kg * 8 + 2 * jj;
                bw[nt][kt].i[jj] = pack2bf(W2[(size_t)k0 * 64 + nt * 16 + n15],
                                           W2[(size_t)(k0 + 1) * 64 + nt * 16 + n15]);
            }
    float b2v[4];
#pragma unroll
    for (int nt = 0; nt < 4; ++nt) b2v[nt] = b2p[nt * 16 + n15];
    __syncthreads();

    int wid = (blockIdx.x * blockDim.x + tid) >> 6;
    int nw = (gridDim.x * blockDim.x) >> 6;
    for (int n = wid; n < N; n += nw) {
        int beg = rowstart[n], end = rowstart[n + 1];
        int d = end - beg;
        float na0 = 0.f, na1 = 0.f, na2 = 0.f, na3 = 0.f;
        for (int t0 = beg; t0 < end; t0 += 16) {
            int e = t0 + n15;
            int ec = (e < end) ? e : beg;
            int2 ep = epack[ec];
            int src = ep.x & 0x1FFFFFF;
            int sg = (int)(((unsigned)ep.x) >> 25);
            float f = __int_as_float(ep.y);
            int sgb = sg << 6;
            int sx = sg & 7;
            const unsigned short* gp = Gbf + (size_t)src * 64 + kg * 8;
            int4 ga = *(const int4*)gp;
            int4 gb = *(const int4*)(gp + 32);
            int q0 = (kg * 2) ^ sx;
            int q1 = (kg * 2 + 1) ^ sx;
            int q2 = (kg * 2 + 8) ^ sx;
            int q3 = (kg * 2 + 9) ^ sx;
            float4 ta0 = *(const float4*)&sA[sgb + (q0 << 2)];
            float4 tb0 = *(const float4*)&sB[sgb + (q0 << 2)];
            float4 ta1 = *(const float4*)&sA[sgb + (q1 << 2)];
            float4 tb1 = *(const float4*)&sB[sgb + (q1 << 2)];
            float4 ta2 = *(const float4*)&sA[sgb + (q2 << 2)];
            float4 tb2 = *(const float4*)&sB[sgb + (q2 << 2)];
            float4 ta3 = *(const float4*)&sA[sgb + (q3 << 2)];
            float4 tb3 = *(const float4*)&sB[sgb + (q3 << 2)];
            float h0 = fmaxf(bflo(ga.x) + fmaf(f, tb0.x, ta0.x), 0.f);
            float h1 = fmaxf(bfhi(ga.x) + fmaf(f, tb0.y, ta0.y), 0.f);
            float h2 = fmaxf(bflo(ga.y) + fmaf(f, tb0.z, ta0.z), 0.f);
            float h3 = fmaxf(bfhi(ga.y) + fmaf(f, tb0.w, ta0.w), 0.f);
            float h4 = fmaxf(bflo(ga.z) + fmaf(f, tb1.x, ta1.x), 0.f);
            float h5 = fmaxf(bfhi(ga.z) + fmaf(f, tb1.y, ta1.y), 0.f);
            float h6 = fmaxf(bflo(ga.w) + fmaf(f, tb1.z, ta1.z), 0.f);
            float h7 = fmaxf(bfhi(ga.w) + fmaf(f, tb1.w, ta1.w), 0.f);
            float h8 = fmaxf(bflo(gb.x) + fmaf(f, tb2.x, ta2.x), 0.f);
            float h9 = fmaxf(bfhi(gb.x) + fmaf(f, tb2.y, ta2.y), 0.f);
            float h10 = fmaxf(bflo(gb.y) + fmaf(f, tb2.z, ta2.z), 0.f);
            float h11 = fmaxf(bfhi(gb.y) + fmaf(f, tb2.w, ta2.w), 0.f);
            float h12 = fmaxf(bflo(gb.z) + fmaf(f, tb3.x, ta3.x), 0.f);
            float h13 = fmaxf(bfhi(gb.z) + fmaf(f, tb3.y, ta3.y), 0.f);
            float h14 = fmaxf(bflo(gb.w) + fmaf(f, tb3.z, ta3.z), 0.f);
            float h15 = fmaxf(bfhi(gb.w) + fmaf(f, tb3.w, ta3.w), 0.f);
            ABFrag A0, A1;
            A0.i[0] = pack2bf(h0, h1);
            A0.i[1] = pack2bf(h2, h3);
            A0.i[2] = pack2bf(h4, h5);
            A0.i[3] = pack2bf(h6, h7);
            A1.i[0] = pack2bf(h8, h9);
            A1.i[1] = pack2bf(h10, h11);
            A1.i[2] = pack2bf(h12, h13);
            A1.i[3] = pack2bf(h14, h15);
            f32x4 acc[4];
#pragma unroll
            for (int nt = 0; nt < 4; ++nt) {
                acc[nt][0] = b2v[nt]; acc[nt][1] = b2v[nt];
                acc[nt][2] = b2v[nt]; acc[nt][3] = b2v[nt];
            }
#pragma unroll
            for (int nt = 0; nt < 4; ++nt) {
                acc[nt] = __builtin_amdgcn_mfma_f32_16x16x32_bf16(A0.v, bw[nt][0].v, acc[nt], 0, 0, 0);
                acc[nt] = __builtin_amdgcn_mfma_f32_16x16x32_bf16(A1.v, bw[nt][1].v, acc[nt], 0, 0, 0);
            }
            int rem = end - t0;
            float rs0, rs1, rs2, rs3;
            {
                float m0 = (kg * 4 + 0 < rem) ? fmaxf(acc[0][0], 0.f) : 0.f;
                float m1 = (kg * 4 + 1 < rem) ? fmaxf(acc[0][1], 0.f) : 0.f;
                float m2 = (kg * 4 + 2 < rem) ? fmaxf(acc[0][2], 0.f) : 0.f;
                float m3 = (kg * 4 + 3 < rem) ? fmaxf(acc[0][3], 0.f) : 0.f;
                rs0 = (m0 + m1) + (m2 + m3);
            }
            {
                float m0 = (kg * 4 + 0 < rem) ? fmaxf(acc[1][0], 0.f) : 0.f;
                float m1 = (kg * 4 + 1 < rem) ? fmaxf(acc[1][1], 0.f) : 0.f;
                float m2 = (kg * 4 + 2 < rem) ? fmaxf(acc[1][2], 0.f) : 0.f;
                float m3 = (kg * 4 + 3 < rem) ? fmaxf(acc[1][3], 0.f) : 0.f;
                rs1 = (m0 + m1) + (m2 + m3);
            }
            {
                float m0 = (kg * 4 + 0 < rem) ? fmaxf(acc[2][0], 0.f) : 0.f;
                float m1 = (kg * 4 + 1 < rem) ? fmaxf(acc[2][1], 0.f) : 0.f;
                float m2 = (kg * 4 + 2 < rem) ? fmaxf(acc[2][2], 0.f) : 0.f;
                float m3 = (kg * 4 + 3 < rem) ? fmaxf(acc[2][3], 0.f) : 0.f;
                rs2 = (m0 + m1) + (m2 + m3);
            }
            {
                float m0 = (kg * 4 + 0 < rem) ? fmaxf(acc[3][0], 0.f) : 0.f;
                float m1 = (kg * 4 + 1 < rem) ? fmaxf(acc[3][1], 0.f) : 0.f;
                float m2 = (kg * 4 + 2 < rem) ? fmaxf(acc[3][2], 0.f) : 0.f;
                float m3 = (kg * 4 + 3 < rem) ? fmaxf(acc[3][3], 0.f) : 0.f;
                rs3 = (m0 + m1) + (m2 + m3);
            }
            rs0 += __shfl_xor(rs0, 16); rs0 += __shfl_xor(rs0, 32);
            rs1 += __shfl_xor(rs1, 16); rs1 += __shfl_xor(rs1, 32);
            rs2 += __shfl_xor(rs2, 16); rs2 += __shfl_xor(rs2, 32);
            rs3 += __shfl_xor(rs3, 16); rs3 += __shfl_xor(rs3, 32);
            na0 += rs0; na1 += rs1; na2 += rs2; na3 += rs3;
        }
        float invd = (d > 0) ? (1.f / (float)d) : 1.f;
        if (kg == 0) {
            Agg[(size_t)n * 64 + 0 * 16 + n15] = na0 * invd;
            Agg[(size_t)n * 64 + 1 * 16 + n15] = na1 * invd;
            Agg[(size_t)n * 64 + 2 * 16 + n15] = na2 * invd;
            Agg[(size_t)n * 64 + 3 * 16 + n15] = na3 * invd;
        }
    }
}

// fused head: t = relu(X1@W1+b1); pred = t@W2+b2; out = 2pi*sigmoid(pred)
__global__ __launch_bounds__(256, 2)
void headf_kernel(const float* __restrict__ X1, const float* __restrict__ W1,
                  const float* __restrict__ b1, const float* __restrict__ W2,
                  const float* __restrict__ b2, float* __restrict__ out, int N) {
    int tid = threadIdx.x, lane = tid & 63;
    int n15 = lane & 15, kg = lane >> 4;
    ABFrag bw[4][2];
#pragma unroll
    for (int nt = 0; nt < 4; ++nt)
#pragma unroll
        for (int kt = 0; kt < 2; ++kt)
#pragma unroll
            for (int jj = 0; jj < 4; ++jj) {
                int k0 = kt * 32 + kg * 8 + 2 * jj;
                bw[nt][kt].i[jj] = pack2bf(W1[(size_t)k0 * 64 + nt * 16 + n15],
                                           W1[(size_t)(k0 + 1) * 64 + nt * 16 + n15]);
            }
    float bv[4];
#pragma unroll
    for (int nt = 0; nt < 4; ++nt) bv[nt] = b1[nt * 16 + n15];
    float w2r[3][4];
#pragma unroll
    for (int nt = 0; nt < 4; ++nt) {
        int col = nt * 16 + n15;
        w2r[0][nt] = W2[col * 3 + 0];
        w2r[1][nt] = W2[col * 3 + 1];
        w2r[2][nt] = W2[col * 3 + 2];
    }
    float b20 = b2[0], b21 = b2[1], b22 = b2[2];
    const float TWO_PI = 6.283185307179586f;

    int wid = (blockIdx.x * blockDim.x + tid) >> 6;
    int nw = (gridDim.x * blockDim.x) >> 6;
    int nTiles = (N + 15) >> 4;
    for (int t = wid; t < nTiles; t += nw) {
        int n0 = t << 4;
        int row = n0 + n15; if (row > N - 1) row = N - 1;
        const float* xp = X1 + (size_t)row * 64 + kg * 8;
        float4 xa = *(const float4*)xp;
        float4 xb = *(const float4*)(xp + 4);
        float4 xc = *(const float4*)(xp + 32);
        float4 xd = *(const float4*)(xp + 36);
        ABFrag A0, A1;
        A0.i[0] = pack2bf(xa.x, xa.y); A0.i[1] = pack2bf(xa.z, xa.w);
        A0.i[2] = pack2bf(xb.x, xb.y); A0.i[3] = pack2bf(xb.z, xb.w);
        A1.i[0] = pack2bf(xc.x, xc.y); A1.i[1] = pack2bf(xc.z, xc.w);
        A1.i[2] = pack2bf(xd.x, xd.y); A1.i[3] = pack2bf(xd.z, xd.w);
        f32x4 acc[4];
#pragma unroll
        for (int nt = 0; nt < 4; ++nt) {
            acc[nt][0] = bv[nt]; acc[nt][1] = bv[nt];
            acc[nt][2] = bv[nt]; acc[nt][3] = bv[nt];
        }
#pragma unroll
        for (int nt = 0; nt < 4; ++nt) {
            acc[nt] = __builtin_amdgcn_mfma_f32_16x16x32_bf16(A0.v, bw[nt][0].v, acc[nt], 0, 0, 0);
            acc[nt] = __builtin_amdgcn_mfma_f32_16x16x32_bf16(A1.v, bw[nt][1].v, acc[nt], 0, 0, 0);
        }
#pragma unroll
        for (int r = 0; r < 4; ++r) {
            float p0 = 0.f, p1 = 0.f, p2 = 0.f;
#pragma unroll
            for (int nt = 0; nt < 4; ++nt) {
                float tv = fmaxf(acc[nt][r], 0.f);
                p0 = fmaf(tv, w2r[0][nt], p0);
                p1 = fmaf(tv, w2r[1][nt], p1);
                p2 = fmaf(tv, w2r[2][nt], p2);
            }
#pragma unroll
            for (int off = 1; off <= 8; off <<= 1) {
                p0 += __shfl_xor(p0, off);
                p1 += __shfl_xor(p1, off);
                p2 += __shfl_xor(p2, off);
            }
            int rr = n0 + kg * 4 + r;
            if (n15 == 0 && rr < N) {
                float v0 = p0 + b20, v1 = p1 + b21, v2 = p2 + b22;
                out[rr * 3 + 0] = TWO_PI / (1.f + expf(-v0));
                out[rr * 3 + 1] = TWO_PI / (1.f + expf(-v1));
                out[rr * 3 + 2] = TWO_PI / (1.f + expf(-v2));
            }
        }
    }
}

extern "C" void kernel_launch(void* const* d_in, const int* in_sizes, int n_in,
                              void* d_out, int out_size, void* d_ws, size_t ws_size,
                              hipStream_t stream) {
    const float* nf    = (const float*)d_in[0];
    const int*   ei    = (const int*)d_in[1];
    const float* ef    = (const float*)d_in[2];
    const float* encW1 = (const float*)d_in[3];
    const float* encb1 = (const float*)d_in[4];
    const float* encW2 = (const float*)d_in[5];
    const float* encb2 = (const float*)d_in[6];
    const float* eeW   = (const float*)d_in[7];
    const float* eeb   = (const float*)d_in[8];
    const float* mW1   = (const float*)d_in[9];
    const float* mb1   = (const float*)d_in[10];
    const float* mW2   = (const float*)d_in[11];
    const float* mb2   = (const float*)d_in[12];
    const float* uW1   = (const float*)d_in[13];
    const float* ub1   = (const float*)d_in[14];
    const float* uW2   = (const float*)d_in[15];
    const float* ub2   = (const float*)d_in[16];
    const float* oW1   = (const float*)d_in[17];
    const float* ob1   = (const float*)d_in[18];
    const float* oW2   = (const float*)d_in[19];
    const float* ob2   = (const float*)d_in[20];
    float* out = (float*)d_out;

    int N = in_sizes[0] / 5;   // 50000
    int E = in_sizes[2];       // 800000
    size_t N64 = (size_t)N * 64;

    float* ws = (float*)d_ws;
    float* f0 = ws;                 // rotating h/agg/free
    float* f1 = f0 + N64;
    float* f2 = f1 + N64;
    unsigned short* gbf = (unsigned short*)(f2 + N64);   // N64 bf16
    int2* epack = (int2*)(f2 + N64 + N64 / 2);           // E int2
    float* bp   = (float*)(epack + E);                   // 64
    float* Atab = bp + 64;                               // 3*65*64
    float* Btab = Atab + 3 * 65 * 64;                    // 3*65*64
    int* rowstart = (int*)(Btab + 3 * 65 * 64);          // N+8
    int* cursor   = rowstart + N + 8;                    // N
    int* dcnt     = cursor + N;                          // N
    int* bsum     = dcnt + N;                            // SCAN_B

    int gemmBlocks = ((N + 15) / 16 + 3) / 4;            // 1 tile per wave

    // piecewise-linear tables for the edge-encoder->W1b path
    bp_kernel<<<1, 64, 0, stream>>>(eeW, eeb, bp);
    tab_kernel<<<195, 64, 0, stream>>>(eeW, eeb, mW1, bp, Atab, Btab);

    // node encoder
    enc1_kernel<<<512, 256, 0, stream>>>(nf, encW1, encb1, f2, N);
    ngemm_kernel<1, 0><<<gemmBlocks, 256, 0, stream>>>(f2, encW2, encb2, f0, N);

    // CSR build (dst-sorted edge list), multi-block scan
    zero_int_kernel<<<256, 256, 0, stream>>>(dcnt, N);
    hist_kernel<<<(E + 255) / 256, 256, 0, stream>>>(ei, dcnt, E);
    scan_part_kernel<<<SCAN_B, 256, 0, stream>>>(dcnt, bsum, N);
    scan_mid_kernel<<<1, SCAN_B, 0, stream>>>(bsum);
    scan_final_kernel<<<SCAN_B, 256, 0, stream>>>(dcnt, bsum, rowstart, cursor, N);
    fill_kernel<<<(E + 255) / 256, 256, 0, stream>>>(ei, ef, bp, cursor, epack, E);

    float* h  = f0;
    float* ag = f1;
    float* fr = f2;
    for (int l = 0; l < 3; ++l) {
        const float* W1a = mW1 + (size_t)l * 128 * 64;
        const float* b1  = mb1 + l * 64;
        const float* W2  = mW2 + (size_t)l * 64 * 64;
        const float* b2  = mb2 + l * 64;
        // gbf = bf16(h @ W1a + b1)
        ngemm_kernel<0, 1><<<gemmBlocks, 256, 0, stream>>>(h, W1a, b1, gbf, N);
        // ag = mean over in-edges of relu(relu(G+ce)@W2+b2)
        msg_mfma_kernel<<<1024, 256, 0, stream>>>(gbf, rowstart, epack,
                                                  Atab + (size_t)l * 65 * 64,
                                                  Btab + (size_t)l * 65 * 64,
                                                  W2, b2, ag, N);
        const float* U1 = uW1 + (size_t)l * 128 * 64;
        const float* v1 = ub1 + l * 64;
        const float* U2 = uW2 + (size_t)l * 64 * 64;
        const float* v2 = ub2 + l * 64;
        // fr = relu( relu([h|ag]@U1+v1) @ U2 + v2 )
        upd_kernel<<<gemmBlocks, 256, 0, stream>>>(h, ag, U1, v1, U2, v2, fr, N);
        float* tmp = h; h = fr; fr = ag; ag = tmp;
    }

    headf_kernel<<<gemmBlocks, 256, 0, stream>>>(h, oW1, ob1, oW2, ob2, out, N);
}

// Round 8
// 348.376 us; speedup vs baseline: 11.5117x; 1.0230x over previous
//
#include <hip/hip_runtime.h>
#include <math.h>

typedef short bf16x8 __attribute__((ext_vector_type(8)));
typedef float f32x4 __attribute__((ext_vector_type(4)));

union ABFrag { int i[4]; bf16x8 v; };

__device__ __forceinline__ float readlane_f(float v, int l) {
    return __uint_as_float(__builtin_amdgcn_readlane(__float_as_uint(v), l));
}

// pack two f32 -> two bf16 (RNE) in one u32 (lo = a, hi = b)
__device__ __forceinline__ int pack2bf(float a, float b) {
    unsigned ua = __float_as_uint(a);
    unsigned ub = __float_as_uint(b);
    ua = (ua + 0x7FFFu + ((ua >> 16) & 1u)) >> 16;
    ub = (ub + 0x7FFFu + ((ub >> 16) & 1u)) & 0xFFFF0000u;
    return (int)(ua | ub);
}
__device__ __forceinline__ float bflo(int d) { return __uint_as_float((unsigned)d << 16); }
__device__ __forceinline__ float bfhi(int d) { return __uint_as_float((unsigned)d & 0xFFFF0000u); }

__global__ void zero_int_kernel(int* __restrict__ p, int n) {
    int i = blockIdx.x * blockDim.x + threadIdx.x;
    int stride = gridDim.x * blockDim.x;
    for (; i < n; i += stride) p[i] = 0;
}

// XCD-localized histogram: class (blockIdx&7) handles dst range only
__global__ __launch_bounds__(256)
void hist_kernel(const int* __restrict__ EI, int* __restrict__ cnt, int E, int N) {
    int x = blockIdx.x & 7;
    int sl = blockIdx.x >> 3;
    int nsl = gridDim.x >> 3;
    int R = (N + 7) >> 3;
    int lo = x * R;
    int hi = lo + R; if (hi > N) hi = N;
    for (int e = sl * 256 + threadIdx.x; e < E; e += nsl * 256) {
        int dst = EI[E + e];
        if (dst >= lo && dst < hi) atomicAdd(&cnt[dst], 1);
    }
}

// ---- multi-block exclusive scan: cnt[N] -> rowstart[N+1], cursor[N] ----
#define SCAN_B 256

__global__ __launch_bounds__(256)
void scan_part_kernel(const int* __restrict__ cnt, int* __restrict__ bsum, int N) {
    int per = (N + gridDim.x - 1) / gridDim.x;
    int lo = blockIdx.x * per;
    int hi = lo + per; if (hi > N) hi = N;
    int s = 0;
    for (int i = lo + threadIdx.x; i < hi; i += 256) s += cnt[i];
#pragma unroll
    for (int off = 32; off >= 1; off >>= 1) s += __shfl_xor(s, off);
    __shared__ int ws[4];
    if ((threadIdx.x & 63) == 0) ws[threadIdx.x >> 6] = s;
    __syncthreads();
    if (threadIdx.x == 0) bsum[blockIdx.x] = ws[0] + ws[1] + ws[2] + ws[3];
}

__global__ __launch_bounds__(SCAN_B)
void scan_mid_kernel(int* __restrict__ bsum) {
    __shared__ int sbuf[SCAN_B];
    int tid = threadIdx.x;
    int v = bsum[tid];
    sbuf[tid] = v;
    __syncthreads();
#pragma unroll
    for (int d = 1; d < SCAN_B; d <<= 1) {
        int t = (tid >= d) ? sbuf[tid - d] : 0;
        __syncthreads();
        sbuf[tid] += t;
        __syncthreads();
    }
    bsum[tid] = sbuf[tid] - v;   // exclusive
}

__global__ __launch_bounds__(256)
void scan_final_kernel(const int* __restrict__ cnt, const int* __restrict__ bsum,
                       int* __restrict__ rowstart, int* __restrict__ cursor, int N) {
    __shared__ int sbuf[256];
    __shared__ int sbase;
    int per = (N + gridDim.x - 1) / gridDim.x;
    int lo = blockIdx.x * per;
    int hi = lo + per; if (hi > N) hi = N;
    if (threadIdx.x == 0) sbase = bsum[blockIdx.x];
    __syncthreads();
    for (int base = lo; base < hi; base += 256) {
        int i = base + threadIdx.x;
        int v = (i < hi) ? cnt[i] : 0;
        sbuf[threadIdx.x] = v;
        __syncthreads();
#pragma unroll
        for (int d = 1; d < 256; d <<= 1) {
            int t = (threadIdx.x >= d) ? sbuf[threadIdx.x - d] : 0;
            __syncthreads();
            sbuf[threadIdx.x] += t;
            __syncthreads();
        }
        if (i < hi) {
            int ex = sbase + sbuf[threadIdx.x] - v;
            rowstart[i] = ex;
            cursor[i] = ex;
        }
        __syncthreads();
        if (threadIdx.x == 0) sbase += sbuf[255];
        __syncthreads();
    }
    if (blockIdx.x == gridDim.x - 1 && threadIdx.x == 0) rowstart[N] = sbase;
}

// XCD-localized scatter: class (blockIdx&7) writes only its dst range
__global__ __launch_bounds__(256)
void fill_kernel(const int* __restrict__ EI, const float* __restrict__ EF,
                 const float* __restrict__ bp, int* __restrict__ cursor,
                 int2* __restrict__ epack, int E, int N) {
    __shared__ float sbp[64];
    if (threadIdx.x < 64) sbp[threadIdx.x] = bp[threadIdx.x];
    __syncthreads();
    int x = blockIdx.x & 7;
    int sl = blockIdx.x >> 3;
    int nsl = gridDim.x >> 3;
    int R = (N + 7) >> 3;
    int lo = x * R;
    int hi = lo + R; if (hi > N) hi = N;
    for (int e = sl * 256 + threadIdx.x; e < E; e += nsl * 256) {
        int dst = EI[E + e];
        if (dst >= lo && dst < hi) {
            int slot = atomicAdd(&cursor[dst], 1);
            float f = EF[e];
            int sg = 0;
#pragma unroll
            for (int st = 32; st >= 1; st >>= 1)
                if (sg + st <= 64 && sbp[sg + st - 1] < f) sg += st;
            epack[slot] = make_int2(EI[e] | (sg << 25), __float_as_int(f));
        }
    }
}

// sorted breakpoints of f -> relu(f*eW+eB): t_k = -eB_k/eW_k (eW_k != 0)
__global__ __launch_bounds__(64)
void bp_kernel(const float* __restrict__ eW, const float* __restrict__ eB,
               float* __restrict__ bp) {
    int lane = threadIdx.x;
    float w = eW[lane], b = eB[lane];
    float t = (w != 0.f) ? (-b / w) : 1e30f;
    __shared__ float sbp[64];
    int rank = 0;
    for (int j = 0; j < 64; ++j) {
        float tj = readlane_f(t, j);
        rank += (tj < t) || (tj == t && j < lane);
    }
    sbp[rank] = t;
    __syncthreads();
    bp[lane] = sbp[lane];
}

// per (layer, segment): A[j] = sum_{k active} eB_k*W1b[k][j], B[j] = sum eW_k*W1b[k][j]
__global__ __launch_bounds__(64)
void tab_kernel(const float* __restrict__ eW, const float* __restrict__ eB,
                const float* __restrict__ mW1, const float* __restrict__ bp,
                float* __restrict__ Atab, float* __restrict__ Btab) {
    int s = blockIdx.x % 65;
    int l = blockIdx.x / 65;
    int j = threadIdx.x;
    float lo = (s == 0) ? 0.f : bp[s - 1];
    float hi = (s == 64) ? 0.f : bp[s];
    float rep;
    if (s == 0) rep = hi - fmaxf(1.f, fabsf(hi));
    else if (s == 64) rep = lo + fmaxf(1.f, fabsf(lo));
    else rep = 0.5f * (lo + hi);
    const float* W1b = mW1 + (size_t)l * 128 * 64 + 64 * 64;
    float A = 0.f, B = 0.f;
    for (int k = 0; k < 64; ++k) {
        float w = eW[k], b = eB[k];
        if (fmaf(rep, w, b) > 0.f) {
            float wv = W1b[k * 64 + j];
            A = fmaf(b, wv, A);
            B = fmaf(w, wv, B);
        }
    }
    Atab[((size_t)l * 65 + s) * 64 + j] = A;
    Btab[((size_t)l * 65 + s) * 64 + j] = B;
}

// first encoder layer: Y[n,j] = relu(b[j] + sum_{k<5} NF[n,k]*W[k,j])
__global__ __launch_bounds__(256)
void enc1_kernel(const float* __restrict__ NF, const float* __restrict__ W,
                 const float* __restrict__ b, float* __restrict__ Y, int N) {
    int lane = threadIdx.x & 63;
    float w0 = W[0 * 64 + lane], w1 = W[1 * 64 + lane], w2 = W[2 * 64 + lane];
    float w3 = W[3 * 64 + lane], w4 = W[4 * 64 + lane];
    float bv = b[lane];
    int wid = (blockIdx.x * blockDim.x + threadIdx.x) >> 6;
    int nw = (gridDim.x * blockDim.x) >> 6;
    for (int n = wid; n < N; n += nw) {
        float x = (lane < 5) ? NF[n * 5 + lane] : 0.f;
        float acc = bv;
        acc = fmaf(readlane_f(x, 0), w0, acc);
        acc = fmaf(readlane_f(x, 1), w1, acc);
        acc = fmaf(readlane_f(x, 2), w2, acc);
        acc = fmaf(readlane_f(x, 3), w3, acc);
        acc = fmaf(readlane_f(x, 4), w4, acc);
        Y[n * 64 + lane] = fmaxf(acc, 0.f);
    }
}

// MFMA node-gemm: Y[n,:] = act( X1[n,:] @ W + b ), K=64, 16 rows/wave-tile.
template <int IN_BF16, int RELU, int OUT_BF16>
__global__ __launch_bounds__(256, 2)
void ngemm_kernel(const void* __restrict__ X1v, const float* __restrict__ W,
                  const float* __restrict__ b, void* __restrict__ Yv, int N) {
    int tid = threadIdx.x;
    int lane = tid & 63;
    int n15 = lane & 15, kg = lane >> 4;
    ABFrag bw[4][2];
#pragma unroll
    for (int nt = 0; nt < 4; ++nt)
#pragma unroll
        for (int kt = 0; kt < 2; ++kt)
#pragma unroll
            for (int jj = 0; jj < 4; ++jj) {
                int k0 = kt * 32 + kg * 8 + 2 * jj;
                bw[nt][kt].i[jj] = pack2bf(W[(size_t)k0 * 64 + nt * 16 + n15],
                                           W[(size_t)(k0 + 1) * 64 + nt * 16 + n15]);
            }
    float bv[4];
#pragma unroll
    for (int nt = 0; nt < 4; ++nt) bv[nt] = b[nt * 16 + n15];

    int wid = (blockIdx.x * blockDim.x + tid) >> 6;
    int nw = (gridDim.x * blockDim.x) >> 6;
    int nTiles = (N + 15) >> 4;
    for (int t = wid; t < nTiles; t += nw) {
        int n0 = t << 4;
        int row = n0 + n15; if (row > N - 1) row = N - 1;
        ABFrag A0, A1;
        if constexpr (IN_BF16) {
            const unsigned short* X = (const unsigned short*)X1v;
            const unsigned short* xp = X + (size_t)row * 64 + kg * 8;
            *(int4*)A0.i = *(const int4*)xp;
            *(int4*)A1.i = *(const int4*)(xp + 32);
        } else {
            const float* X = (const float*)X1v;
            const float* xp = X + (size_t)row * 64 + kg * 8;
            float4 xa = *(const float4*)xp;
            float4 xb = *(const float4*)(xp + 4);
            float4 xc = *(const float4*)(xp + 32);
            float4 xd = *(const float4*)(xp + 36);
            A0.i[0] = pack2bf(xa.x, xa.y); A0.i[1] = pack2bf(xa.z, xa.w);
            A0.i[2] = pack2bf(xb.x, xb.y); A0.i[3] = pack2bf(xb.z, xb.w);
            A1.i[0] = pack2bf(xc.x, xc.y); A1.i[1] = pack2bf(xc.z, xc.w);
            A1.i[2] = pack2bf(xd.x, xd.y); A1.i[3] = pack2bf(xd.z, xd.w);
        }
        f32x4 acc[4];
#pragma unroll
        for (int nt = 0; nt < 4; ++nt) {
            acc[nt][0] = bv[nt]; acc[nt][1] = bv[nt];
            acc[nt][2] = bv[nt]; acc[nt][3] = bv[nt];
        }
#pragma unroll
        for (int nt = 0; nt < 4; ++nt) {
            acc[nt] = __builtin_amdgcn_mfma_f32_16x16x32_bf16(A0.v, bw[nt][0].v, acc[nt], 0, 0, 0);
            acc[nt] = __builtin_amdgcn_mfma_f32_16x16x32_bf16(A1.v, bw[nt][1].v, acc[nt], 0, 0, 0);
        }
        if constexpr (OUT_BF16) {
            unsigned short* Y = (unsigned short*)Yv;
            bool ev = ((n15 & 1) == 0);
#pragma unroll
            for (int nt = 0; nt < 4; ++nt) {
                float v0 = acc[nt][0], v1 = acc[nt][1], v2 = acc[nt][2], v3 = acc[nt][3];
                if (RELU) {
                    v0 = fmaxf(v0, 0.f); v1 = fmaxf(v1, 0.f);
                    v2 = fmaxf(v2, 0.f); v3 = fmaxf(v3, 0.f);
                }
                float o0 = __shfl_xor(v0, 1), o1 = __shfl_xor(v1, 1);
                float o2 = __shfl_xor(v2, 1), o3 = __shfl_xor(v3, 1);
                int colb = nt * 16 + (n15 & ~1);
                if (ev) {
                    int r0 = n0 + kg * 4 + 0, r1 = n0 + kg * 4 + 1;
                    if (r0 < N) *(int*)(Y + (size_t)r0 * 64 + colb) = pack2bf(v0, o0);
                    if (r1 < N) *(int*)(Y + (size_t)r1 * 64 + colb) = pack2bf(v1, o1);
                } else {
                    int r2 = n0 + kg * 4 + 2, r3 = n0 + kg * 4 + 3;
                    if (r2 < N) *(int*)(Y + (size_t)r2 * 64 + colb) = pack2bf(o2, v2);
                    if (r3 < N) *(int*)(Y + (size_t)r3 * 64 + colb) = pack2bf(o3, v3);
                }
            }
        } else {
            float* Y = (float*)Yv;
#pragma unroll
            for (int nt = 0; nt < 4; ++nt)
#pragma unroll
                for (int r = 0; r < 4; ++r) {
                    int rr = n0 + kg * 4 + r;
                    if (rr < N) {
                        float v = acc[nt][r];
                        if (RELU) v = fmaxf(v, 0.f);
                        Y[(size_t)rr * 64 + nt * 16 + n15] = v;
                    }
                }
        }
    }
}

// fused update MLP: Y = relu( relu([X1|X2]@U1 + v1) @ U2 + v2 ), X1 bf16, X2 f32, Y bf16
__global__ __launch_bounds__(256, 2)
void upd_kernel(const unsigned short* __restrict__ X1, const float* __restrict__ X2,
                const float* __restrict__ U1, const float* __restrict__ v1,
                const float* __restrict__ U2, const float* __restrict__ v2,
                unsigned short* __restrict__ Y, int N) {
    __shared__ unsigned short sT[4][16 * 72];
    int tid = threadIdx.x, lane = tid & 63, w = tid >> 6;
    int n15 = lane & 15, kg = lane >> 4;
    unsigned short* T = sT[w];

    ABFrag bw1[4][4], bw2[4][2];
#pragma unroll
    for (int nt = 0; nt < 4; ++nt) {
#pragma unroll
        for (int kt = 0; kt < 4; ++kt)
#pragma unroll
            for (int jj = 0; jj < 4; ++jj) {
                int k0 = kt * 32 + kg * 8 + 2 * jj;
                bw1[nt][kt].i[jj] = pack2bf(U1[(size_t)k0 * 64 + nt * 16 + n15],
                                            U1[(size_t)(k0 + 1) * 64 + nt * 16 + n15]);
            }
#pragma unroll
        for (int kt = 0; kt < 2; ++kt)
#pragma unroll
            for (int jj = 0; jj < 4; ++jj) {
                int k0 = kt * 32 + kg * 8 + 2 * jj;
                bw2[nt][kt].i[jj] = pack2bf(U2[(size_t)k0 * 64 + nt * 16 + n15],
                                            U2[(size_t)(k0 + 1) * 64 + nt * 16 + n15]);
            }
    }
    float b1v[4], b2v[4];
#pragma unroll
    for (int nt = 0; nt < 4; ++nt) { b1v[nt] = v1[nt * 16 + n15]; b2v[nt] = v2[nt * 16 + n15]; }

    int wid = (blockIdx.x * blockDim.x + tid) >> 6;
    int nw = (gridDim.x * blockDim.x) >> 6;
    int nTiles = (N + 15) >> 4;
    for (int t = wid; t < nTiles; t += nw) {
        int n0 = t << 4;
        int row = n0 + n15; if (row > N - 1) row = N - 1;
        ABFrag A0, A1, A2, A3;
        const unsigned short* xp = X1 + (size_t)row * 64 + kg * 8;
        *(int4*)A0.i = *(const int4*)xp;
        *(int4*)A1.i = *(const int4*)(xp + 32);
        const float* yp = X2 + (size_t)row * 64 + kg * 8;
        float4 ya = *(const float4*)yp;
        float4 yb = *(const float4*)(yp + 4);
        float4 yc = *(const float4*)(yp + 32);
        float4 yd = *(const float4*)(yp + 36);
        A2.i[0] = pack2bf(ya.x, ya.y); A2.i[1] = pack2bf(ya.z, ya.w);
        A2.i[2] = pack2bf(yb.x, yb.y); A2.i[3] = pack2bf(yb.z, yb.w);
        A3.i[0] = pack2bf(yc.x, yc.y); A3.i[1] = pack2bf(yc.z, yc.w);
        A3.i[2] = pack2bf(yd.x, yd.y); A3.i[3] = pack2bf(yd.z, yd.w);
        f32x4 a1[4];
#pragma unroll
        for (int nt = 0; nt < 4; ++nt) {
            a1[nt][0] = b1v[nt]; a1[nt][1] = b1v[nt];
            a1[nt][2] = b1v[nt]; a1[nt][3] = b1v[nt];
        }
#pragma unroll
        for (int nt = 0; nt < 4; ++nt) {
            a1[nt] = __builtin_amdgcn_mfma_f32_16x16x32_bf16(A0.v, bw1[nt][0].v, a1[nt], 0, 0, 0);
            a1[nt] = __builtin_amdgcn_mfma_f32_16x16x32_bf16(A1.v, bw1[nt][1].v, a1[nt], 0, 0, 0);
            a1[nt] = __builtin_amdgcn_mfma_f32_16x16x32_bf16(A2.v, bw1[nt][2].v, a1[nt], 0, 0, 0);
            a1[nt] = __builtin_amdgcn_mfma_f32_16x16x32_bf16(A3.v, bw1[nt][3].v, a1[nt], 0, 0, 0);
        }
        // t (relu, bf16) -> per-wave LDS tile, stride 72
        asm volatile("s_waitcnt lgkmcnt(0)" ::: "memory");
        __builtin_amdgcn_sched_barrier(0);
        bool ev = ((n15 & 1) == 0);
#pragma unroll
        for (int nt = 0; nt < 4; ++nt) {
            float v0 = fmaxf(a1[nt][0], 0.f), v1 = fmaxf(a1[nt][1], 0.f);
            float v2 = fmaxf(a1[nt][2], 0.f), v3 = fmaxf(a1[nt][3], 0.f);
            float o0 = __shfl_xor(v0, 1), o1 = __shfl_xor(v1, 1);
            float o2 = __shfl_xor(v2, 1), o3 = __shfl_xor(v3, 1);
            int colb = nt * 16 + (n15 & ~1);
            if (ev) {
                *(int*)(T + (kg * 4 + 0) * 72 + colb) = pack2bf(v0, o0);
                *(int*)(T + (kg * 4 + 1) * 72 + colb) = pack2bf(v1, o1);
            } else {
                *(int*)(T + (kg * 4 + 2) * 72 + colb) = pack2bf(o2, v2);
                *(int*)(T + (kg * 4 + 3) * 72 + colb) = pack2bf(o3, v3);
            }
        }
        asm volatile("s_waitcnt lgkmcnt(0)" ::: "memory");
        __builtin_amdgcn_sched_barrier(0);
        ABFrag T0, T1;
        *(int4*)T0.i = *(const int4*)(T + n15 * 72 + kg * 8);
        *(int4*)T1.i = *(const int4*)(T + n15 * 72 + 32 + kg * 8);
        f32x4 a2[4];
#pragma unroll
        for (int nt = 0; nt < 4; ++nt) {
            a2[nt][0] = b2v[nt]; a2[nt][1] = b2v[nt];
            a2[nt][2] = b2v[nt]; a2[nt][3] = b2v[nt];
        }
#pragma unroll
        for (int nt = 0; nt < 4; ++nt) {
            a2[nt] = __builtin_amdgcn_mfma_f32_16x16x32_bf16(T0.v, bw2[nt][0].v, a2[nt], 0, 0, 0);
            a2[nt] = __builtin_amdgcn_mfma_f32_16x16x32_bf16(T1.v, bw2[nt][1].v, a2[nt], 0, 0, 0);
        }
#pragma unroll
        for (int nt = 0; nt < 4; ++nt) {
            float v0 = fmaxf(a2[nt][0], 0.f), v1 = fmaxf(a2[nt][1], 0.f);
            float v2 = fmaxf(a2[nt][2], 0.f), v3 = fmaxf(a2[nt][3], 0.f);
            float o0 = __shfl_xor(v0, 1), o1 = __shfl_xor(v1, 1);
            float o2 = __shfl_xor(v2, 1), o3 = __shfl_xor(v3, 1);
            int colb = nt * 16 + (n15 & ~1);
            if (ev) {
                int r0 = n0 + kg * 4 + 0, r1 = n0 + kg * 4 + 1;
                if (r0 < N) *(int*)(Y + (size_t)r0 * 64 + colb) = pack2bf(v0, o0);
                if (r1 < N) *(int*)(Y + (size_t)r1 * 64 + colb) = pack2bf(v1, o1);
            } else {
                int r2 = n0 + kg * 4 + 2, r3 = n0 + kg * 4 + 3;
                if (r2 < N) *(int*)(Y + (size_t)r2 * 64 + colb) = pack2bf(o2, v2);
                if (r3 < N) *(int*)(Y + (size_t)r3 * 64 + colb) = pack2bf(o3, v3);
            }
        }
    }
}

// node-per-wave MFMA message kernel (no atomics); packed bf16 A|B table in LDS
__global__ __launch_bounds__(256, 4)
void msg_mfma_kernel(const unsigned short* __restrict__ Gbf, const int* __restrict__ rowstart,
                     const int2* __restrict__ epack,
                     const float* __restrict__ Atab, const float* __restrict__ Btab,
                     const float* __restrict__ W2, const float* __restrict__ b2p,
                     float* __restrict__ Agg, int N) {
    __shared__ int sT[65 * 64];
    int tid = threadIdx.x;
    for (int i = tid; i < 65 * 64; i += 256) {
        int sgi = i >> 6, c = i & 63;
        int pos = (sgi << 6) + ((((c >> 2) ^ (sgi & 7)) << 2) | (c & 3));
        sT[pos] = pack2bf(Atab[i], Btab[i]);   // lo = A, hi = B
    }
    int lane = tid & 63;
    int n15 = lane & 15;
    int kg = lane >> 4;

    ABFrag bw[4][2];
#pragma unroll
    for (int nt = 0; nt < 4; ++nt)
#pragma unroll
        for (int kt = 0; kt < 2; ++kt)
#pragma unroll
            for (int jj = 0; jj < 4; ++jj) {
                int k0 = kt * 32 + kg * 8 + 2 * jj;
                bw[nt][kt].i[jj] = pack2bf(W2[(size_t)k0 * 64 + nt * 16 + n15],
                                           W2[(size_t)(k0 + 1) * 64 + nt * 16 + n15]);
            }
    float b2v[4];
#pragma unroll
    for (int nt = 0; nt < 4; ++nt) b2v[nt] = b2p[nt * 16 + n15];
    __syncthreads();

    int wid = (blockIdx.x * blockDim.x + tid) >> 6;
    int nw = (gridDim.x * blockDim.x) >> 6;
    for (int n = wid; n < N; n += nw) {
        int beg = rowstart[n], end = rowstart[n + 1];
        int d = end - beg;
        float na0 = 0.f, na1 = 0.f, na2 = 0.f, na3 = 0.f;
        for (int t0 = beg; t0 < end; t0 += 16) {
            int e = t0 + n15;
            int ec = (e < end) ? e : beg;
            int2 ep = epack[ec];
            int src = ep.x & 0x1FFFFFF;
            int sg = (int)(((unsigned)ep.x) >> 25);
            float f = __int_as_float(ep.y);
            int sgb = sg << 6;
            int sx = sg & 7;
            const unsigned short* gp = Gbf + (size_t)src * 64 + kg * 8;
            int4 ga = *(const int4*)gp;
            int4 gb = *(const int4*)(gp + 32);
            int q0 = (kg * 2) ^ sx;
            int q1 = (kg * 2 + 1) ^ sx;
            int q2 = (kg * 2 + 8) ^ sx;
            int q3 = (kg * 2 + 9) ^ sx;
            int4 t0v = *(const int4*)&sT[sgb + (q0 << 2)];
            int4 t1v = *(const int4*)&sT[sgb + (q1 << 2)];
            int4 t2v = *(const int4*)&sT[sgb + (q2 << 2)];
            int4 t3v = *(const int4*)&sT[sgb + (q3 << 2)];
            float h0 = fmaxf(bflo(ga.x) + fmaf(f, bfhi(t0v.x), bflo(t0v.x)), 0.f);
            float h1 = fmaxf(bfhi(ga.x) + fmaf(f, bfhi(t0v.y), bflo(t0v.y)), 0.f);
            float h2 = fmaxf(bflo(ga.y) + fmaf(f, bfhi(t0v.z), bflo(t0v.z)), 0.f);
            float h3 = fmaxf(bfhi(ga.y) + fmaf(f, bfhi(t0v.w), bflo(t0v.w)), 0.f);
            float h4 = fmaxf(bflo(ga.z) + fmaf(f, bfhi(t1v.x), bflo(t1v.x)), 0.f);
            float h5 = fmaxf(bfhi(ga.z) + fmaf(f, bfhi(t1v.y), bflo(t1v.y)), 0.f);
            float h6 = fmaxf(bflo(ga.w) + fmaf(f, bfhi(t1v.z), bflo(t1v.z)), 0.f);
            float h7 = fmaxf(bfhi(ga.w) + fmaf(f, bfhi(t1v.w), bflo(t1v.w)), 0.f);
            float h8 = fmaxf(bflo(gb.x) + fmaf(f, bfhi(t2v.x), bflo(t2v.x)), 0.f);
            float h9 = fmaxf(bfhi(gb.x) + fmaf(f, bfhi(t2v.y), bflo(t2v.y)), 0.f);
            float h10 = fmaxf(bflo(gb.y) + fmaf(f, bfhi(t2v.z), bflo(t2v.z)), 0.f);
            float h11 = fmaxf(bfhi(gb.y) + fmaf(f, bfhi(t2v.w), bflo(t2v.w)), 0.f);
            float h12 = fmaxf(bflo(gb.z) + fmaf(f, bfhi(t3v.x), bflo(t3v.x)), 0.f);
            float h13 = fmaxf(bfhi(gb.z) + fmaf(f, bfhi(t3v.y), bflo(t3v.y)), 0.f);
            float h14 = fmaxf(bflo(gb.w) + fmaf(f, bfhi(t3v.z), bflo(t3v.z)), 0.f);
            float h15 = fmaxf(bfhi(gb.w) + fmaf(f, bfhi(t3v.w), bflo(t3v.w)), 0.f);
            ABFrag A0, A1;
            A0.i[0] = pack2bf(h0, h1);
            A0.i[1] = pack2bf(h2, h3);
            A0.i[2] = pack2bf(h4, h5);
            A0.i[3] = pack2bf(h6, h7);
            A1.i[0] = pack2bf(h8, h9);
            A1.i[1] = pack2bf(h10, h11);
            A1.i[2] = pack2bf(h12, h13);
            A1.i[3] = pack2bf(h14, h15);
            f32x4 acc[4];
#pragma unroll
            for (int nt = 0; nt < 4; ++nt) {
                acc[nt][0] = b2v[nt]; acc[nt][1] = b2v[nt];
                acc[nt][2] = b2v[nt]; acc[nt][3] = b2v[nt];
            }
#pragma unroll
            for (int nt = 0; nt < 4; ++nt) {
                acc[nt] = __builtin_amdgcn_mfma_f32_16x16x32_bf16(A0.v, bw[nt][0].v, acc[nt], 0, 0, 0);
                acc[nt] = __builtin_amdgcn_mfma_f32_16x16x32_bf16(A1.v, bw[nt][1].v, acc[nt], 0, 0, 0);
            }
            int rem = end - t0;
            float rs0, rs1, rs2, rs3;
            {
                float m0 = (kg * 4 + 0 < rem) ? fmaxf(acc[0][0], 0.f) : 0.f;
                float m1 = (kg * 4 + 1 < rem) ? fmaxf(acc[0][1], 0.f) : 0.f;
                float m2 = (kg * 4 + 2 < rem) ? fmaxf(acc[0][2], 0.f) : 0.f;
                float m3 = (kg * 4 + 3 < rem) ? fmaxf(acc[0][3], 0.f) : 0.f;
                rs0 = (m0 + m1) + (m2 + m3);
            }
            {
                float m0 = (kg * 4 + 0 < rem) ? fmaxf(acc[1][0], 0.f) : 0.f;
                float m1 = (kg * 4 + 1 < rem) ? fmaxf(acc[1][1], 0.f) : 0.f;
                float m2 = (kg * 4 + 2 < rem) ? fmaxf(acc[1][2], 0.f) : 0.f;
                float m3 = (kg * 4 + 3 < rem) ? fmaxf(acc[1][3], 0.f) : 0.f;
                rs1 = (m0 + m1) + (m2 + m3);
            }
            {
                float m0 = (kg * 4 + 0 < rem) ? fmaxf(acc[2][0], 0.f) : 0.f;
                float m1 = (kg * 4 + 1 < rem) ? fmaxf(acc[2][1], 0.f) : 0.f;
                float m2 = (kg * 4 + 2 < rem) ? fmaxf(acc[2][2], 0.f) : 0.f;
                float m3 = (kg * 4 + 3 < rem) ? fmaxf(acc[2][3], 0.f) : 0.f;
                rs2 = (m0 + m1) + (m2 + m3);
            }
            {
                float m0 = (kg * 4 + 0 < rem) ? fmaxf(acc[3][0], 0.f) : 0.f;
                float m1 = (kg * 4 + 1 < rem) ? fmaxf(acc[3][1], 0.f) : 0.f;
                float m2 = (kg * 4 + 2 < rem) ? fmaxf(acc[3][2], 0.f) : 0.f;
                float m3 = (kg * 4 + 3 < rem) ? fmaxf(acc[3][3], 0.f) : 0.f;
                rs3 = (m0 + m1) + (m2 + m3);
            }
            rs0 += __shfl_xor(rs0, 16); rs0 += __shfl_xor(rs0, 32);
            rs1 += __shfl_xor(rs1, 16); rs1 += __shfl_xor(rs1, 32);
            rs2 += __shfl_xor(rs2, 16); rs2 += __shfl_xor(rs2, 32);
            rs3 += __shfl_xor(rs3, 16); rs3 += __shfl_xor(rs3, 32);
            na0 += rs0; na1 += rs1; na2 += rs2; na3 += rs3;
        }
        float invd = (d > 0) ? (1.f / (float)d) : 1.f;
        // lane holds sums for cols nt*16+n15; lane (kg,n15) stores col kg*16+n15 = lane
        float v = na0;
        v = (kg == 1) ? na1 : v;
        v = (kg == 2) ? na2 : v;
        v = (kg == 3) ? na3 : v;
        Agg[(size_t)n * 64 + lane] = v * invd;
    }
}

// fused head: t = relu(X1@W1+b1); pred = t@W2+b2; out = 2pi*sigmoid(pred); X1 bf16
__global__ __launch_bounds__(256, 2)
void headf_kernel(const unsigned short* __restrict__ X1, const float* __restrict__ W1,
                  const float* __restrict__ b1, const float* __restrict__ W2,
                  const float* __restrict__ b2, float* __restrict__ out, int N) {
    int tid = threadIdx.x, lane = tid & 63;
    int n15 = lane & 15, kg = lane >> 4;
    ABFrag bw[4][2];
#pragma unroll
    for (int nt = 0; nt < 4; ++nt)
#pragma unroll
        for (int kt = 0; kt < 2; ++kt)
#pragma unroll
            for (int jj = 0; jj < 4; ++jj) {
                int k0 = kt * 32 + kg * 8 + 2 * jj;
                bw[nt][kt].i[jj] = pack2bf(W1[(size_t)k0 * 64 + nt * 16 + n15],
                                           W1[(size_t)(k0 + 1) * 64 + nt * 16 + n15]);
            }
    float bv[4];
#pragma unroll
    for (int nt = 0; nt < 4; ++nt) bv[nt] = b1[nt * 16 + n15];
    float w2r[3][4];
#pragma unroll
    for (int nt = 0; nt < 4; ++nt) {
        int col = nt * 16 + n15;
        w2r[0][nt] = W2[col * 3 + 0];
        w2r[1][nt] = W2[col * 3 + 1];
        w2r[2][nt] = W2[col * 3 + 2];
    }
    float b20 = b2[0], b21 = b2[1], b22 = b2[2];
    const float TWO_PI = 6.283185307179586f;

    int wid = (blockIdx.x * blockDim.x + tid) >> 6;
    int nw = (gridDim.x * blockDim.x) >> 6;
    int nTiles = (N + 15) >> 4;
    for (int t = wid; t < nTiles; t += nw) {
        int n0 = t << 4;
        int row = n0 + n15; if (row > N - 1) row = N - 1;
        ABFrag A0, A1;
        const unsigned short* xp = X1 + (size_t)row * 64 + kg * 8;
        *(int4*)A0.i = *(const int4*)xp;
        *(int4*)A1.i = *(const int4*)(xp + 32);
        f32x4 acc[4];
#pragma unroll
        for (int nt = 0; nt < 4; ++nt) {
            acc[nt][0] = bv[nt]; acc[nt][1] = bv[nt];
            acc[nt][2] = bv[nt]; acc[nt][3] = bv[nt];
        }
#pragma unroll
        for (int nt = 0; nt < 4; ++nt) {
            acc[nt] = __builtin_amdgcn_mfma_f32_16x16x32_bf16(A0.v, bw[nt][0].v, acc[nt], 0, 0, 0);
            acc[nt] = __builtin_amdgcn_mfma_f32_16x16x32_bf16(A1.v, bw[nt][1].v, acc[nt], 0, 0, 0);
        }
#pragma unroll
        for (int r = 0; r < 4; ++r) {
            float p0 = 0.f, p1 = 0.f, p2 = 0.f;
#pragma unroll
            for (int nt = 0; nt < 4; ++nt) {
                float tv = fmaxf(acc[nt][r], 0.f);
                p0 = fmaf(tv, w2r[0][nt], p0);
                p1 = fmaf(tv, w2r[1][nt], p1);
                p2 = fmaf(tv, w2r[2][nt], p2);
            }
#pragma unroll
            for (int off = 1; off <= 8; off <<= 1) {
                p0 += __shfl_xor(p0, off);
                p1 += __shfl_xor(p1, off);
                p2 += __shfl_xor(p2, off);
            }
            int rr = n0 + kg * 4 + r;
            if (n15 == 0 && rr < N) {
                float v0 = p0 + b20, v1 = p1 + b21, v2 = p2 + b22;
                out[rr * 3 + 0] = TWO_PI / (1.f + expf(-v0));
                out[rr * 3 + 1] = TWO_PI / (1.f + expf(-v1));
                out[rr * 3 + 2] = TWO_PI / (1.f + expf(-v2));
            }
        }
    }
}

extern "C" void kernel_launch(void* const* d_in, const int* in_sizes, int n_in,
                              void* d_out, int out_size, void* d_ws, size_t ws_size,
                              hipStream_t stream) {
    const float* nf    = (const float*)d_in[0];
    const int*   ei    = (const int*)d_in[1];
    const float* ef    = (const float*)d_in[2];
    const float* encW1 = (const float*)d_in[3];
    const float* encb1 = (const float*)d_in[4];
    const float* encW2 = (const float*)d_in[5];
    const float* encb2 = (const float*)d_in[6];
    const float* eeW   = (const float*)d_in[7];
    const float* eeb   = (const float*)d_in[8];
    const float* mW1   = (const float*)d_in[9];
    const float* mb1   = (const float*)d_in[10];
    const float* mW2   = (const float*)d_in[11];
    const float* mb2   = (const float*)d_in[12];
    const float* uW1   = (const float*)d_in[13];
    const float* ub1   = (const float*)d_in[14];
    const float* uW2   = (const float*)d_in[15];
    const float* ub2   = (const float*)d_in[16];
    const float* oW1   = (const float*)d_in[17];
    const float* ob1   = (const float*)d_in[18];
    const float* oW2   = (const float*)d_in[19];
    const float* ob2   = (const float*)d_in[20];
    float* out = (float*)d_out;

    int N = in_sizes[0] / 5;   // 50000
    int E = in_sizes[2];       // 800000
    size_t N64 = (size_t)N * 64;

    float* ws = (float*)d_ws;
    float* f2  = ws;                                     // N64 f32 (enc tmp)
    float* agg = f2 + N64;                               // N64 f32
    unsigned short* hA  = (unsigned short*)(agg + N64);  // N64 bf16
    unsigned short* hB  = hA + N64;                      // N64 bf16
    unsigned short* gbf = hB + N64;                      // N64 bf16
    int2* epack = (int2*)(gbf + N64);                    // E int2
    float* bp   = (float*)(epack + E);                   // 64
    float* Atab = bp + 64;                               // 3*65*64
    float* Btab = Atab + 3 * 65 * 64;                    // 3*65*64
    int* rowstart = (int*)(Btab + 3 * 65 * 64);          // N+8
    int* cursor   = rowstart + N + 8;                    // N
    int* dcnt     = cursor + N;                          // N
    int* bsum     = dcnt + N;                            // SCAN_B

    int gemmBlocks = ((N + 15) / 16 + 3) / 4;            // 1 tile per wave

    // piecewise-linear tables for the edge-encoder->W1b path
    bp_kernel<<<1, 64, 0, stream>>>(eeW, eeb, bp);
    tab_kernel<<<195, 64, 0, stream>>>(eeW, eeb, mW1, bp, Atab, Btab);

    // node encoder
    enc1_kernel<<<512, 256, 0, stream>>>(nf, encW1, encb1, f2, N);
    ngemm_kernel<0, 1, 1><<<gemmBlocks, 256, 0, stream>>>(f2, encW2, encb2, hA, N);

    // CSR build (dst-sorted edge list), XCD-localized hist/scatter
    zero_int_kernel<<<256, 256, 0, stream>>>(dcnt, N);
    hist_kernel<<<2048, 256, 0, stream>>>(ei, dcnt, E, N);
    scan_part_kernel<<<SCAN_B, 256, 0, stream>>>(dcnt, bsum, N);
    scan_mid_kernel<<<1, SCAN_B, 0, stream>>>(bsum);
    scan_final_kernel<<<SCAN_B, 256, 0, stream>>>(dcnt, bsum, rowstart, cursor, N);
    fill_kernel<<<2048, 256, 0, stream>>>(ei, ef, bp, cursor, epack, E, N);

    unsigned short* h  = hA;
    unsigned short* hn = hB;
    for (int l = 0; l < 3; ++l) {
        const float* W1a = mW1 + (size_t)l * 128 * 64;
        const float* b1  = mb1 + l * 64;
        const float* W2  = mW2 + (size_t)l * 64 * 64;
        const float* b2  = mb2 + l * 64;
        // gbf = bf16(h @ W1a + b1)
        ngemm_kernel<1, 0, 1><<<gemmBlocks, 256, 0, stream>>>(h, W1a, b1, gbf, N);
        // agg = mean over in-edges of relu(relu(G+ce)@W2+b2)
        msg_mfma_kernel<<<1024, 256, 0, stream>>>(gbf, rowstart, epack,
                                                  Atab + (size_t)l * 65 * 64,
                                                  Btab + (size_t)l * 65 * 64,
                                                  W2, b2, agg, N);
        const float* U1 = uW1 + (size_t)l * 128 * 64;
        const float* v1 = ub1 + l * 64;
        const float* U2 = uW2 + (size_t)l * 64 * 64;
        const float* v2 = ub2 + l * 64;
        // hn = relu( relu([h|agg]@U1+v1) @ U2 + v2 )
        upd_kernel<<<gemmBlocks, 256, 0, stream>>>(h, agg, U1, v1, U2, v2, hn, N);
        unsigned short* tmp = h; h = hn; hn = tmp;
    }

    headf_kernel<<<gemmBlocks, 256, 0, stream>>>(h, oW1, ob1, oW2, ob2, out, N);
}